// Round 4
// baseline (435.195 us; speedup 1.0000x reference)
//
#include <hip/hip_runtime.h>
#include <hip/hip_bf16.h>
#include <math.h>

// Node classifier: KProp(K=2, gcn_norm) -> SAGEConv(64->64)+selu -> SAGEConv(64->40) -> softmax
// N=100000, E=1600000, D=H=64, C=40.
//
// R16 = R15 with layer 2 fully fused into the mean-gather:
//   sage2_softmax_kernel: gather h1 -> agg2 (fp32, in regs) -> logits = [agg2|h1]@W2+b2
//   (W2 fp32 in LDS, staged AFTER the gather so it hides under stragglers) -> softmax -> out.
//   Kills gemm2_softmax kernel + agg2 write/read round-trip (~26 MB).
//   init_bcursor folded into hipMemsetAsync + relative cursors (-1 launch).

#define RFL(x) __builtin_amdgcn_readfirstlane(x)
#define BK_SHIFT 10        // coarse bucket = dst>>10 (1024 nodes)
#define MAXBUCK 256

typedef short bf16x8 __attribute__((ext_vector_type(8)));
typedef float f32x4 __attribute__((ext_vector_type(4)));
typedef unsigned short ushort8v __attribute__((ext_vector_type(8)));

__device__ __forceinline__ float bf2f(unsigned short u) {
    return __uint_as_float((unsigned)u << 16);
}
__device__ __forceinline__ unsigned short f2bf(float f) {
    __hip_bfloat16 b = __float2bfloat16(f);   // RTN
    return *reinterpret_cast<unsigned short*>(&b);
}

// ---------------- CSR build ----------------

// Phase 1: block-private coarse bucket partition; packed u32 (src<<10 | dst&1023).
// bcursor[] starts at 0 (memset); holds per-bucket relative fill count.
__global__ __launch_bounds__(256) void partition_kernel(const int* __restrict__ src,
                                                        const int* __restrict__ dst,
                                                        int* __restrict__ bcursor,
                                                        unsigned int* __restrict__ temp,
                                                        int e, int nbuck, int cap) {
    __shared__ int bc[MAXBUCK];
    int t = threadIdx.x;
    int chunk = (e + gridDim.x - 1) / gridDim.x;
    int base = blockIdx.x * chunk;
    int cnt = e - base;
    if (cnt > chunk) cnt = chunk;
    if (cnt < 0) cnt = 0;
    for (int j = t; j < nbuck; j += 256) bc[j] = 0;
    __syncthreads();
    for (int i = t; i < cnt; i += 256) {
        int d = dst[base + i];
        atomicAdd(&bc[d >> BK_SHIFT], 1);
    }
    __syncthreads();
    for (int j = t; j < nbuck; j += 256) {
        int c = bc[j];
        bc[j] = (c > 0) ? (atomicAdd(&bcursor[j], c) + j * cap) : 0;
    }
    __syncthreads();
    for (int i = t; i < cnt; i += 256) {
        int s = src[base + i];
        int d = dst[base + i];
        int bk = d >> BK_SHIFT;
        int p = atomicAdd(&bc[bk], 1);
        if (p < (bk + 1) * cap) temp[p] = ((unsigned int)s << BK_SHIFT) | (unsigned int)(d & 1023);
    }
}

// Phase 2: per-bucket counting sort by node_local + deg/dis/cnt_inv/row_ptr.
__global__ __launch_bounds__(256) void bucket_csr_kernel(const unsigned int* __restrict__ temp,
                                                         const int* __restrict__ bcursor,
                                                         int* __restrict__ row_ptr,
                                                         float* __restrict__ dis,
                                                         float* __restrict__ cnt_inv,
                                                         int* __restrict__ csr_src,
                                                         int n, int cap, int nbuck, int e) {
    __shared__ int cnt3[1024];
    __shared__ int part[256];
    int b = blockIdx.x;
    int t = threadIdx.x;
    int nbeg = b << BK_SHIFT;
    int cj = 0;
    if (t < nbuck) {
        cj = bcursor[t];
        if (cj > cap) cj = cap;
    }
    part[t] = cj;
    __syncthreads();
    for (int off = 1; off < 256; off <<= 1) {
        int u = (t >= off) ? part[t - off] : 0;
        __syncthreads();
        part[t] += u;
        __syncthreads();
    }
    int cntb = bcursor[b];
    if (cntb > cap) cntb = cap;
    int bbase = part[b] - cntb;
    __syncthreads();
    for (int i = t; i < 1024; i += 256) cnt3[i] = 0;
    __syncthreads();
    const unsigned int* tb = temp + (size_t)b * cap;
    for (int i = t; i < cntb; i += 256) {
        atomicAdd(&cnt3[tb[i] & 1023u], 1);
    }
    __syncthreads();
    int d0 = cnt3[t * 4 + 0], d1 = cnt3[t * 4 + 1], d2 = cnt3[t * 4 + 2], d3 = cnt3[t * 4 + 3];
    int run = d0 + d1 + d2 + d3;
    int dd[4] = {d0, d1, d2, d3};
#pragma unroll
    for (int k = 0; k < 4; ++k) {
        int node = nbeg + t * 4 + k;
        if (node < n) {
            float fd = (float)dd[k];
            dis[node] = (dd[k] > 0) ? rsqrtf(fd) : 0.0f;
            cnt_inv[node] = 1.0f / fmaxf(fd, 1.0f);
        }
    }
    __syncthreads();
    part[t] = run;
    __syncthreads();
    for (int off = 1; off < 256; off <<= 1) {
        int u = (t >= off) ? part[t - off] : 0;
        __syncthreads();
        part[t] += u;
        __syncthreads();
    }
    int ex = part[t] - run;
    int oo[4];
    oo[0] = ex; oo[1] = ex + d0; oo[2] = ex + d0 + d1; oo[3] = ex + d0 + d1 + d2;
#pragma unroll
    for (int k = 0; k < 4; ++k) {
        cnt3[t * 4 + k] = oo[k];
        int node = nbeg + t * 4 + k;
        if (node < n) row_ptr[node] = bbase + oo[k];
    }
    if (b == nbuck - 1 && t == 0) row_ptr[n] = e;
    __syncthreads();
    for (int i = t; i < cntb; i += 256) {
        unsigned int ed = tb[i];
        int pos = atomicAdd(&cnt3[ed & 1023u], 1);
        csr_src[bbase + pos] = (int)(ed >> BK_SHIFT);
    }
}

// ---------------- fp32 -> bf16 convert ----------------
__global__ void f2bf_kernel(const float4* __restrict__ in, ushort4* __restrict__ out, int n4) {
    int i = blockIdx.x * blockDim.x + threadIdx.x;
    if (i < n4) {
        float4 v = in[i];
        ushort4 u;
        u.x = f2bf(v.x); u.y = f2bf(v.y); u.z = f2bf(v.z); u.w = f2bf(v.w);
        out[i] = u;
    }
}

// ---------------- KProp propagation over bf16 rows (128B), bf16 out ----------------
// Wave per node. lane = g*16 + l: edge slot g (0..3), feature quad l (0..15).
template <int TAG>
__global__ __launch_bounds__(256) void prop4bf_kernel(const ushort4* __restrict__ in4u,
                                                      ushort4* __restrict__ out4u,
                                                      const int* __restrict__ row_ptr,
                                                      const int* __restrict__ csr_src,
                                                      const float* __restrict__ dis,
                                                      int n) {
    int lane = threadIdx.x & 63;
    int g = lane >> 4;
    int l = lane & 15;
    int node = RFL(blockIdx.x * 4 + (threadIdx.x >> 6));
    if (node >= n) return;
    int beg = row_ptr[node];
    int end = row_ptr[node + 1];
    float4 acc = make_float4(0.f, 0.f, 0.f, 0.f);
    int j = beg;
    for (; j + 16 <= end; j += 16) {
        int s[4];
        ushort4 u[4];
        float w[4];
#pragma unroll
        for (int q = 0; q < 4; ++q) s[q] = csr_src[j + q * 4 + g];
#pragma unroll
        for (int q = 0; q < 4; ++q) u[q] = in4u[(size_t)s[q] * 16 + l];
#pragma unroll
        for (int q = 0; q < 4; ++q) w[q] = dis[s[q]];
#pragma unroll
        for (int q = 0; q < 4; ++q) {
            acc.x += w[q] * bf2f(u[q].x);
            acc.y += w[q] * bf2f(u[q].y);
            acc.z += w[q] * bf2f(u[q].z);
            acc.w += w[q] * bf2f(u[q].w);
        }
    }
    for (; j + 8 <= end; j += 8) {
        int s[2];
        ushort4 u[2];
        float w[2];
#pragma unroll
        for (int q = 0; q < 2; ++q) s[q] = csr_src[j + q * 4 + g];
#pragma unroll
        for (int q = 0; q < 2; ++q) u[q] = in4u[(size_t)s[q] * 16 + l];
#pragma unroll
        for (int q = 0; q < 2; ++q) w[q] = dis[s[q]];
#pragma unroll
        for (int q = 0; q < 2; ++q) {
            acc.x += w[q] * bf2f(u[q].x);
            acc.y += w[q] * bf2f(u[q].y);
            acc.z += w[q] * bf2f(u[q].z);
            acc.w += w[q] * bf2f(u[q].w);
        }
    }
    for (; j < end; j += 4) {
        int idx = j + g;
        bool valid = idx < end;
        int s = csr_src[valid ? idx : (end - 1)];
        float w = valid ? dis[s] : 0.0f;
        ushort4 u = in4u[(size_t)s * 16 + l];
        acc.x += w * bf2f(u.x);
        acc.y += w * bf2f(u.y);
        acc.z += w * bf2f(u.z);
        acc.w += w * bf2f(u.w);
    }
    acc.x += __shfl_xor(acc.x, 16); acc.x += __shfl_xor(acc.x, 32);
    acc.y += __shfl_xor(acc.y, 16); acc.y += __shfl_xor(acc.y, 32);
    acc.z += __shfl_xor(acc.z, 16); acc.z += __shfl_xor(acc.z, 32);
    acc.w += __shfl_xor(acc.w, 16); acc.w += __shfl_xor(acc.w, 32);
    if (g == 0) {
        float sc = dis[node];
        ushort4 o;
        o.x = f2bf(acc.x * sc);
        o.y = f2bf(acc.y * sc);
        o.z = f2bf(acc.z * sc);
        o.w = f2bf(acc.w * sc);
        out4u[(size_t)node * 16 + l] = o;
    }
}

// ---------------- mean-agg over bf16 t1 + selu epilogue, bf16 out ----------------
__global__ __launch_bounds__(256) void prop_mean_bf_kernel(const ushort4* __restrict__ in4u,
                                                           ushort4* __restrict__ out4u,
                                                           const int* __restrict__ row_ptr,
                                                           const int* __restrict__ csr_src,
                                                           const float* __restrict__ cnt_inv,
                                                           const float4* __restrict__ r4,
                                                           const float4* __restrict__ b4,
                                                           int n) {
    int lane = threadIdx.x & 63;
    int g = lane >> 4;
    int l = lane & 15;
    int node = RFL(blockIdx.x * 4 + (threadIdx.x >> 6));
    if (node >= n) return;
    int beg = row_ptr[node];
    int end = row_ptr[node + 1];
    float4 acc = make_float4(0.f, 0.f, 0.f, 0.f);
    int j = beg;
    for (; j + 16 <= end; j += 16) {
        int s[4];
        ushort4 u[4];
#pragma unroll
        for (int q = 0; q < 4; ++q) s[q] = csr_src[j + q * 4 + g];
#pragma unroll
        for (int q = 0; q < 4; ++q) u[q] = in4u[(size_t)s[q] * 16 + l];
#pragma unroll
        for (int q = 0; q < 4; ++q) {
            acc.x += bf2f(u[q].x);
            acc.y += bf2f(u[q].y);
            acc.z += bf2f(u[q].z);
            acc.w += bf2f(u[q].w);
        }
    }
    for (; j + 8 <= end; j += 8) {
        int s[2];
        ushort4 u[2];
#pragma unroll
        for (int q = 0; q < 2; ++q) s[q] = csr_src[j + q * 4 + g];
#pragma unroll
        for (int q = 0; q < 2; ++q) u[q] = in4u[(size_t)s[q] * 16 + l];
#pragma unroll
        for (int q = 0; q < 2; ++q) {
            acc.x += bf2f(u[q].x);
            acc.y += bf2f(u[q].y);
            acc.z += bf2f(u[q].z);
            acc.w += bf2f(u[q].w);
        }
    }
    for (; j < end; j += 4) {
        int idx = j + g;
        bool valid = idx < end;
        int s = csr_src[valid ? idx : (end - 1)];
        float w = valid ? 1.0f : 0.0f;
        ushort4 u = in4u[(size_t)s * 16 + l];
        acc.x += w * bf2f(u.x);
        acc.y += w * bf2f(u.y);
        acc.z += w * bf2f(u.z);
        acc.w += w * bf2f(u.w);
    }
    acc.x += __shfl_xor(acc.x, 16); acc.x += __shfl_xor(acc.x, 32);
    acc.y += __shfl_xor(acc.y, 16); acc.y += __shfl_xor(acc.y, 32);
    acc.z += __shfl_xor(acc.z, 16); acc.z += __shfl_xor(acc.z, 32);
    acc.w += __shfl_xor(acc.w, 16); acc.w += __shfl_xor(acc.w, 32);
    if (g == 0) {
        float sc = cnt_inv[node];
        float4 ra = r4[(size_t)node * 16 + l];
        float4 bb = b4[l];
        const float scale = 1.0507009873554805f;
        const float alpha = 1.6732632423543772f;
        float t0 = acc.x * sc + ra.x + bb.x;
        float t1 = acc.y * sc + ra.y + bb.y;
        float t2 = acc.z * sc + ra.z + bb.z;
        float t3 = acc.w * sc + ra.w + bb.w;
        t0 = scale * (t0 > 0.0f ? t0 : alpha * expm1f(t0));
        t1 = scale * (t1 > 0.0f ? t1 : alpha * expm1f(t1));
        t2 = scale * (t2 > 0.0f ? t2 : alpha * expm1f(t2));
        t3 = scale * (t3 > 0.0f ? t3 : alpha * expm1f(t3));
        ushort4 o;
        o.x = f2bf(t0); o.y = f2bf(t1); o.z = f2bf(t2); o.w = f2bf(t3);
        out4u[(size_t)node * 16 + l] = o;
    }
}

// ---------------- fused layer 2: mean-gather(h1) + [agg2|h1]@W2+b2 + softmax ----------------
// Wave per node (4 nodes/block). Gather phase identical to the mean-gather pattern.
// After the wave reduction, g==0 lanes hold agg2 (fp32); stage [agg2|h1_own] to LDS,
// stage W2 (fp32, 20 KB) cooperatively AFTER the gather, then 64-lane dot (col=lane) + softmax.
__global__ __launch_bounds__(256) void sage2_softmax_kernel(const ushort4* __restrict__ in4u,
                                                            float* __restrict__ out,
                                                            const int* __restrict__ row_ptr,
                                                            const int* __restrict__ csr_src,
                                                            const float* __restrict__ cnt_inv,
                                                            const float* __restrict__ Wl2,
                                                            const float* __restrict__ Wr2,
                                                            const float* __restrict__ b2,
                                                            int n) {
    __shared__ float sW[128 * 40];   // [k][c]: k<64 -> Wl2, k>=64 -> Wr2 (20 KB)
    __shared__ float sV[4][128];     // per-wave [agg2|h1_own] (2 KB)
    int t = threadIdx.x;
    int lane = t & 63;
    int g = lane >> 4;
    int l = lane & 15;
    int w = t >> 6;
    int node0 = RFL(blockIdx.x * 4 + w);
    int node = (node0 < n) ? node0 : (n - 1);   // clamp; no early return (block-wide syncs below)
    int beg = row_ptr[node];
    int end = row_ptr[node + 1];
    float4 acc = make_float4(0.f, 0.f, 0.f, 0.f);
    int j = beg;
    for (; j + 16 <= end; j += 16) {
        int s[4];
        ushort4 u[4];
#pragma unroll
        for (int q = 0; q < 4; ++q) s[q] = csr_src[j + q * 4 + g];
#pragma unroll
        for (int q = 0; q < 4; ++q) u[q] = in4u[(size_t)s[q] * 16 + l];
#pragma unroll
        for (int q = 0; q < 4; ++q) {
            acc.x += bf2f(u[q].x);
            acc.y += bf2f(u[q].y);
            acc.z += bf2f(u[q].z);
            acc.w += bf2f(u[q].w);
        }
    }
    for (; j + 8 <= end; j += 8) {
        int s[2];
        ushort4 u[2];
#pragma unroll
        for (int q = 0; q < 2; ++q) s[q] = csr_src[j + q * 4 + g];
#pragma unroll
        for (int q = 0; q < 2; ++q) u[q] = in4u[(size_t)s[q] * 16 + l];
#pragma unroll
        for (int q = 0; q < 2; ++q) {
            acc.x += bf2f(u[q].x);
            acc.y += bf2f(u[q].y);
            acc.z += bf2f(u[q].z);
            acc.w += bf2f(u[q].w);
        }
    }
    for (; j < end; j += 4) {
        int idx = j + g;
        bool valid = idx < end;
        int s = csr_src[valid ? idx : (end - 1)];
        float ww = valid ? 1.0f : 0.0f;
        ushort4 u = in4u[(size_t)s * 16 + l];
        acc.x += ww * bf2f(u.x);
        acc.y += ww * bf2f(u.y);
        acc.z += ww * bf2f(u.z);
        acc.w += ww * bf2f(u.w);
    }
    acc.x += __shfl_xor(acc.x, 16); acc.x += __shfl_xor(acc.x, 32);
    acc.y += __shfl_xor(acc.y, 16); acc.y += __shfl_xor(acc.y, 32);
    acc.z += __shfl_xor(acc.z, 16); acc.z += __shfl_xor(acc.z, 32);
    acc.w += __shfl_xor(acc.w, 16); acc.w += __shfl_xor(acc.w, 32);
    if (g == 0) {
        float sc = cnt_inv[node];
        sV[w][l * 4 + 0] = acc.x * sc;
        sV[w][l * 4 + 1] = acc.y * sc;
        sV[w][l * 4 + 2] = acc.z * sc;
        sV[w][l * 4 + 3] = acc.w * sc;
        ushort4 u = in4u[(size_t)node * 16 + l];
        sV[w][64 + l * 4 + 0] = bf2f(u.x);
        sV[w][64 + l * 4 + 1] = bf2f(u.y);
        sV[w][64 + l * 4 + 2] = bf2f(u.z);
        sV[w][64 + l * 4 + 3] = bf2f(u.w);
    }
    // Stage W2 after the gather (hides under gather stragglers; W is L2-hot after first blocks).
    for (int idx = t; idx < 128 * 40; idx += 256) {
        sW[idx] = (idx < 64 * 40) ? Wl2[idx] : Wr2[idx - 64 * 40];
    }
    __syncthreads();

    // Dot: col = lane (active < 40), k over 128.
    int c = (lane < 40) ? lane : 0;
    float accd = b2[c];
#pragma unroll 8
    for (int k = 0; k < 128; ++k) {
        accd += sV[w][k] * sW[k * 40 + c];
    }
    float x = (lane < 40) ? accd : -INFINITY;
    float m = x;
    m = fmaxf(m, __shfl_xor(m, 1));
    m = fmaxf(m, __shfl_xor(m, 2));
    m = fmaxf(m, __shfl_xor(m, 4));
    m = fmaxf(m, __shfl_xor(m, 8));
    m = fmaxf(m, __shfl_xor(m, 16));
    m = fmaxf(m, __shfl_xor(m, 32));
    float e = (lane < 40) ? __expf(x - m) : 0.0f;
    float s = e;
    s += __shfl_xor(s, 1);
    s += __shfl_xor(s, 2);
    s += __shfl_xor(s, 4);
    s += __shfl_xor(s, 8);
    s += __shfl_xor(s, 16);
    s += __shfl_xor(s, 32);
    if (lane < 40 && node0 < n) {
        out[(size_t)node0 * 40 + lane] = e / s;
    }
}

// ---------------- MFMA GEMM (layer 1): [outL(bf16)|outR(fp32)] = in_bf16(N x 64) @ [Wl|Wr] ----------------
// Block = 64 nodes x OC cols, 4 waves; wave = 16-node band x all OC cols.
// Weights fp32 split into bf16 hi + bf16 residual; both MFMA'd into the same fp32 acc.
// LDS tiles [row][k] bf16, XOR-swizzled: 16B-chunk index kb ^= (row&7).
template <int OC>
__global__ __launch_bounds__(256) void gemm_mfma_kernel(const unsigned short* __restrict__ in,
                                                        const float* __restrict__ Wl,
                                                        const float* __restrict__ Wr,
                                                        const float* __restrict__ bias,
                                                        __hip_bfloat16* __restrict__ outL,
                                                        float* __restrict__ outR,
                                                        int n, int add_bias) {
    constexpr int HC = OC / 2;
    constexpr int NF = OC / 16;          // n-frags per wave
    __shared__ unsigned short sA[64 * 64];        // [m][k] swizzled
    __shared__ unsigned short sBh[OC * 64];       // [c][k] swizzled, hi
    __shared__ unsigned short sBr[OC * 64];       // [c][k] swizzled, residual
    int t = threadIdx.x;
    int blk = blockIdx.x;

    // Stage A: 64 nodes x 64 k bf16, 16B chunks. idx -> m = idx>>3, kb = idx&7.
#pragma unroll
    for (int i = 0; i < 2; ++i) {
        int idx = i * 256 + t;
        int m = idx >> 3;
        int kb = idx & 7;
        int node = blk * 64 + m;
        if (node >= n) node = n - 1;
        ushort8v v = *reinterpret_cast<const ushort8v*>(in + (size_t)node * 64 + kb * 8);
        *reinterpret_cast<ushort8v*>(&sA[m * 64 + ((kb ^ (m & 7)) << 3)]) = v;
    }
    // Stage B: [Wl|Wr] fp32 64k x OC -> bf16 hi/res, transposed to [c][k].
    for (int idx = t; idx < 64 * OC; idx += 256) {
        int k = idx / OC;
        int c = idx - k * OC;
        float v = (c < HC) ? Wl[k * HC + c] : Wr[k * HC + (c - HC)];
        unsigned short hi = f2bf(v);
        unsigned short re = f2bf(v - bf2f(hi));
        int pos = c * 64 + (((k >> 3) ^ (c & 7)) << 3) + (k & 7);
        sBh[pos] = hi;
        sBr[pos] = re;
    }
    __syncthreads();

    int w = t >> 6;          // wave id: m-band [w*16, w*16+16)
    int lane = t & 63;
    int r = lane & 15;
    int q = lane >> 4;       // k-block within MFMA
    int m = w * 16 + r;      // A row for input frags
    // A frags: k-chunks (s*4+q) for MFMA k-step s
    bf16x8 A0 = *reinterpret_cast<const bf16x8*>(&sA[m * 64 + (((0 + q) ^ (r & 7)) << 3)]);
    bf16x8 A1 = *reinterpret_cast<const bf16x8*>(&sA[m * 64 + (((4 + q) ^ (r & 7)) << 3)]);

    f32x4 acc[NF];
#pragma unroll
    for (int c = 0; c < NF; ++c) acc[c] = (f32x4)(0.0f);

#pragma unroll
    for (int c = 0; c < NF; ++c) {
        int cb = c * 16 + r;
        bf16x8 B0 = *reinterpret_cast<const bf16x8*>(&sBh[cb * 64 + (((0 + q) ^ (r & 7)) << 3)]);
        bf16x8 B1 = *reinterpret_cast<const bf16x8*>(&sBh[cb * 64 + (((4 + q) ^ (r & 7)) << 3)]);
        bf16x8 R0 = *reinterpret_cast<const bf16x8*>(&sBr[cb * 64 + (((0 + q) ^ (r & 7)) << 3)]);
        bf16x8 R1 = *reinterpret_cast<const bf16x8*>(&sBr[cb * 64 + (((4 + q) ^ (r & 7)) << 3)]);
        acc[c] = __builtin_amdgcn_mfma_f32_16x16x32_bf16(A0, B0, acc[c], 0, 0, 0);
        acc[c] = __builtin_amdgcn_mfma_f32_16x16x32_bf16(A1, B1, acc[c], 0, 0, 0);
        acc[c] = __builtin_amdgcn_mfma_f32_16x16x32_bf16(A0, R0, acc[c], 0, 0, 0);
        acc[c] = __builtin_amdgcn_mfma_f32_16x16x32_bf16(A1, R1, acc[c], 0, 0, 0);
    }

    // Epilogue: C/D frag: col = c*16 + (lane&15), row = (lane>>4)*4 + j (within wave's band).
#pragma unroll
    for (int c = 0; c < NF; ++c) {
        int col = c * 16 + r;
#pragma unroll
        for (int j = 0; j < 4; ++j) {
            int node = blk * 64 + w * 16 + q * 4 + j;
            if (node < n) {
                float v = acc[c][j];
                if (col < HC) {
                    outL[(size_t)node * HC + col] = __float2bfloat16(v);
                } else {
                    outR[(size_t)node * HC + (col - HC)] = v + (add_bias ? bias[col - HC] : 0.0f);
                }
            }
        }
    }
}

// ---------------- launch ----------------

extern "C" void kernel_launch(void* const* d_in, const int* in_sizes, int n_in,
                              void* d_out, int out_size, void* d_ws, size_t ws_size,
                              hipStream_t stream) {
    const float* x   = (const float*)d_in[0];
    const float* Wl1 = (const float*)d_in[1];
    const float* Wr1 = (const float*)d_in[2];
    const float* b1  = (const float*)d_in[3];
    const float* Wl2 = (const float*)d_in[4];
    const float* Wr2 = (const float*)d_in[5];
    const float* b2  = (const float*)d_in[6];
    const int* edge_src = (const int*)d_in[7];
    const int* edge_dst = (const int*)d_in[8];
    float* out = (float*)d_out;

    const int N = in_sizes[0] / 64;
    const int E = in_sizes[7];
    const int NBUCK = (N + (1 << BK_SHIFT) - 1) >> BK_SHIFT;   // 98
    size_t buf_bytes = (size_t)N * 64 * 4;
    int cap = E / NBUCK + E / (2 * NBUCK) + 1024;              // mean + 50% + slack
    int cap_max = (int)(buf_bytes / ((size_t)NBUCK * 4));
    if (cap > cap_max) cap = cap_max;

    size_t off = 0;
    auto carve = [&](size_t bytes) -> void* {
        void* p = (char*)d_ws + off;
        off = (off + bytes + 255) & ~(size_t)255;
        return p;
    };
    int*          row_ptr = (int*)carve((size_t)(N + 1) * 4);
    int*          bcursor = (int*)carve((size_t)NBUCK * 4);
    float*        dis     = (float*)carve((size_t)N * 4);
    float*        cnt_inv = (float*)carve((size_t)N * 4);
    int*          csr_src = (int*)carve((size_t)E * 4);
    char*         bufA    = (char*)carve(buf_bytes);
    char*         bufB    = (char*)carve(buf_bytes);
    float*        bufC    = (float*)carve(buf_bytes);          // temp / r1
    unsigned int* temp    = (unsigned int*)bufC;               // dead before r1 written
    (void)ws_size;

    // bf16 sub-buffers (sequenced so nothing live overlaps):
    unsigned short* xb  = (unsigned short*)bufA;                         // x bf16
    unsigned short* p0b = (unsigned short*)(bufA + buf_bytes / 2);       // p0 bf16
    unsigned short* hb  = (unsigned short*)bufB;                         // h bf16
    unsigned short* t1b = (unsigned short*)bufA;                         // t1 bf16 (xb dead)
    unsigned short* h1b = (unsigned short*)bufB;                         // h1 bf16 (hb dead)

    const int nb_node = (N + 3) / 4;
    const int nb_gemm = (N + 63) / 64;
    const int n4 = N * 64 / 4;

    // CSR build (bcursor zeroed via async memset; partition uses relative cursors)
    hipMemsetAsync(bcursor, 0, (size_t)NBUCK * 4, stream);
    partition_kernel<<<256, 256, 0, stream>>>(edge_src, edge_dst, bcursor, temp, E, NBUCK, cap);
    bucket_csr_kernel<<<NBUCK, 256, 0, stream>>>(temp, bcursor, row_ptr, dis, cnt_inv,
                                                 csr_src, N, cap, NBUCK, E);

    // x -> bf16
    f2bf_kernel<<<(n4 + 255) / 256, 256, 0, stream>>>((const float4*)x, (ushort4*)xb, n4);
    // KProp x2: p0 = S x ; h = S p0   (bf16 rows, fp32 accumulate)
    prop4bf_kernel<1><<<nb_node, 256, 0, stream>>>((const ushort4*)xb, (ushort4*)p0b,
                                                   row_ptr, csr_src, dis, N);
    prop4bf_kernel<2><<<nb_node, 256, 0, stream>>>((const ushort4*)p0b, (ushort4*)hb,
                                                   row_ptr, csr_src, dis, N);
    // [t1(bf16)|r1(fp32)] = h @ [Wl1|Wr1]  (MFMA)
    gemm_mfma_kernel<128><<<nb_gemm, 256, 0, stream>>>(hb, Wl1, Wr1, nullptr,
                                                       (__hip_bfloat16*)t1b, bufC, N, 0);
    // h1 = selu(mean(t1) + r1 + b1) -> bf16
    prop_mean_bf_kernel<<<nb_node, 256, 0, stream>>>((const ushort4*)t1b, (ushort4*)h1b,
                                                     row_ptr, csr_src, cnt_inv,
                                                     (const float4*)bufC, (const float4*)b1, N);
    // out = softmax([mean(h1)|h1] @ [Wl2;Wr2] + b2)   (fused gather+GEMM+softmax)
    sage2_softmax_kernel<<<nb_node, 256, 0, stream>>>((const ushort4*)h1b, out, row_ptr,
                                                      csr_src, cnt_inv, Wl2, Wr2, b2, N);
}

// Round 5
// 370.156 us; speedup vs baseline: 1.1757x; 1.1757x over previous
//
#include <hip/hip_runtime.h>
#include <hip/hip_bf16.h>
#include <math.h>

// Node classifier: KProp(K=2, gcn_norm) -> SAGEConv(64->64)+selu -> SAGEConv(64->40) -> softmax
// N=100000, E=1600000, D=H=64, C=40.
//
// R17 = R15 structure (layer-2 = mean-gather + standalone MFMA gemm2_softmax; R16's fused
// LDS-dot epilogue reverted — it was ~83us of LDS-pipe time) with pre-scaled KProp:
//   x' = bf16(dis * x); p0' = dis^2 * sum x'[s]; h = dis * sum p0'[s]
//   (identical algebra to w_e = dis[d]*dis[s]; kills the per-edge dis[src] gather in both rounds)

#define RFL(x) __builtin_amdgcn_readfirstlane(x)
#define BK_SHIFT 10        // coarse bucket = dst>>10 (1024 nodes)
#define MAXBUCK 256

typedef short bf16x8 __attribute__((ext_vector_type(8)));
typedef _Float16 f16x8 __attribute__((ext_vector_type(8)));
typedef float f32x4 __attribute__((ext_vector_type(4)));
typedef unsigned short ushort8v __attribute__((ext_vector_type(8)));

__device__ __forceinline__ float bf2f(unsigned short u) {
    return __uint_as_float((unsigned)u << 16);
}
__device__ __forceinline__ unsigned short f2bf(float f) {
    __hip_bfloat16 b = __float2bfloat16(f);   // RTN
    return *reinterpret_cast<unsigned short*>(&b);
}
__device__ __forceinline__ unsigned short f2h(float f) {
    _Float16 h = (_Float16)f;                 // RTN
    return *reinterpret_cast<unsigned short*>(&h);
}

// ---------------- CSR build ----------------

// Phase 1: block-private coarse bucket partition; packed u32 (src<<10 | dst&1023).
// bcursor[] starts at 0 (memset); holds per-bucket relative fill count.
__global__ __launch_bounds__(256) void partition_kernel(const int* __restrict__ src,
                                                        const int* __restrict__ dst,
                                                        int* __restrict__ bcursor,
                                                        unsigned int* __restrict__ temp,
                                                        int e, int nbuck, int cap) {
    __shared__ int bc[MAXBUCK];
    int t = threadIdx.x;
    int chunk = (e + gridDim.x - 1) / gridDim.x;
    int base = blockIdx.x * chunk;
    int cnt = e - base;
    if (cnt > chunk) cnt = chunk;
    if (cnt < 0) cnt = 0;
    for (int j = t; j < nbuck; j += 256) bc[j] = 0;
    __syncthreads();
    for (int i = t; i < cnt; i += 256) {
        int d = dst[base + i];
        atomicAdd(&bc[d >> BK_SHIFT], 1);
    }
    __syncthreads();
    for (int j = t; j < nbuck; j += 256) {
        int c = bc[j];
        bc[j] = (c > 0) ? (atomicAdd(&bcursor[j], c) + j * cap) : 0;
    }
    __syncthreads();
    for (int i = t; i < cnt; i += 256) {
        int s = src[base + i];
        int d = dst[base + i];
        int bk = d >> BK_SHIFT;
        int p = atomicAdd(&bc[bk], 1);
        if (p < (bk + 1) * cap) temp[p] = ((unsigned int)s << BK_SHIFT) | (unsigned int)(d & 1023);
    }
}

// Phase 2: per-bucket counting sort by node_local + deg/dis/cnt_inv/row_ptr.
__global__ __launch_bounds__(256) void bucket_csr_kernel(const unsigned int* __restrict__ temp,
                                                         const int* __restrict__ bcursor,
                                                         int* __restrict__ row_ptr,
                                                         float* __restrict__ dis,
                                                         float* __restrict__ cnt_inv,
                                                         int* __restrict__ csr_src,
                                                         int n, int cap, int nbuck, int e) {
    __shared__ int cnt3[1024];
    __shared__ int part[256];
    int b = blockIdx.x;
    int t = threadIdx.x;
    int nbeg = b << BK_SHIFT;
    int cj = 0;
    if (t < nbuck) {
        cj = bcursor[t];
        if (cj > cap) cj = cap;
    }
    part[t] = cj;
    __syncthreads();
    for (int off = 1; off < 256; off <<= 1) {
        int u = (t >= off) ? part[t - off] : 0;
        __syncthreads();
        part[t] += u;
        __syncthreads();
    }
    int cntb = bcursor[b];
    if (cntb > cap) cntb = cap;
    int bbase = part[b] - cntb;
    __syncthreads();
    for (int i = t; i < 1024; i += 256) cnt3[i] = 0;
    __syncthreads();
    const unsigned int* tb = temp + (size_t)b * cap;
    for (int i = t; i < cntb; i += 256) {
        atomicAdd(&cnt3[tb[i] & 1023u], 1);
    }
    __syncthreads();
    int d0 = cnt3[t * 4 + 0], d1 = cnt3[t * 4 + 1], d2 = cnt3[t * 4 + 2], d3 = cnt3[t * 4 + 3];
    int run = d0 + d1 + d2 + d3;
    int dd[4] = {d0, d1, d2, d3};
#pragma unroll
    for (int k = 0; k < 4; ++k) {
        int node = nbeg + t * 4 + k;
        if (node < n) {
            float fd = (float)dd[k];
            dis[node] = (dd[k] > 0) ? rsqrtf(fd) : 0.0f;
            cnt_inv[node] = 1.0f / fmaxf(fd, 1.0f);
        }
    }
    __syncthreads();
    part[t] = run;
    __syncthreads();
    for (int off = 1; off < 256; off <<= 1) {
        int u = (t >= off) ? part[t - off] : 0;
        __syncthreads();
        part[t] += u;
        __syncthreads();
    }
    int ex = part[t] - run;
    int oo[4];
    oo[0] = ex; oo[1] = ex + d0; oo[2] = ex + d0 + d1; oo[3] = ex + d0 + d1 + d2;
#pragma unroll
    for (int k = 0; k < 4; ++k) {
        cnt3[t * 4 + k] = oo[k];
        int node = nbeg + t * 4 + k;
        if (node < n) row_ptr[node] = bbase + oo[k];
    }
    if (b == nbuck - 1 && t == 0) row_ptr[n] = e;
    __syncthreads();
    for (int i = t; i < cntb; i += 256) {
        unsigned int ed = tb[i];
        int pos = atomicAdd(&cnt3[ed & 1023u], 1);
        csr_src[bbase + pos] = (int)(ed >> BK_SHIFT);
    }
}

// ---------------- fp32 -> bf16 convert, pre-scaled by dis[node] ----------------
__global__ void f2bf_scale_kernel(const float4* __restrict__ in, ushort4* __restrict__ out,
                                  const float* __restrict__ dis, int n4) {
    int i = blockIdx.x * blockDim.x + threadIdx.x;
    if (i < n4) {
        float d = dis[i >> 4];
        float4 v = in[i];
        ushort4 u;
        u.x = f2bf(v.x * d); u.y = f2bf(v.y * d); u.z = f2bf(v.z * d); u.w = f2bf(v.w * d);
        out[i] = u;
    }
}

// ---------------- KProp propagation: unweighted row-sum, final scale dis^POW ----------------
// Wave per node. lane = g*16 + l: edge slot g (0..3), feature quad l (0..15).
// POW==2: out = dis^2 * sum (round 1, input pre-scaled x'); POW==1: out = dis * sum (round 2).
template <int POW>
__global__ __launch_bounds__(256) void prop4bf_kernel(const ushort4* __restrict__ in4u,
                                                      ushort4* __restrict__ out4u,
                                                      const int* __restrict__ row_ptr,
                                                      const int* __restrict__ csr_src,
                                                      const float* __restrict__ dis,
                                                      int n) {
    int lane = threadIdx.x & 63;
    int g = lane >> 4;
    int l = lane & 15;
    int node = RFL(blockIdx.x * 4 + (threadIdx.x >> 6));
    if (node >= n) return;
    int beg = row_ptr[node];
    int end = row_ptr[node + 1];
    float4 acc = make_float4(0.f, 0.f, 0.f, 0.f);
    int j = beg;
    for (; j + 16 <= end; j += 16) {
        int s[4];
        ushort4 u[4];
#pragma unroll
        for (int q = 0; q < 4; ++q) s[q] = csr_src[j + q * 4 + g];
#pragma unroll
        for (int q = 0; q < 4; ++q) u[q] = in4u[(size_t)s[q] * 16 + l];
#pragma unroll
        for (int q = 0; q < 4; ++q) {
            acc.x += bf2f(u[q].x);
            acc.y += bf2f(u[q].y);
            acc.z += bf2f(u[q].z);
            acc.w += bf2f(u[q].w);
        }
    }
    for (; j + 8 <= end; j += 8) {
        int s[2];
        ushort4 u[2];
#pragma unroll
        for (int q = 0; q < 2; ++q) s[q] = csr_src[j + q * 4 + g];
#pragma unroll
        for (int q = 0; q < 2; ++q) u[q] = in4u[(size_t)s[q] * 16 + l];
#pragma unroll
        for (int q = 0; q < 2; ++q) {
            acc.x += bf2f(u[q].x);
            acc.y += bf2f(u[q].y);
            acc.z += bf2f(u[q].z);
            acc.w += bf2f(u[q].w);
        }
    }
    for (; j < end; j += 4) {
        int idx = j + g;
        bool valid = idx < end;
        int s = csr_src[valid ? idx : (end - 1)];
        float w = valid ? 1.0f : 0.0f;
        ushort4 u = in4u[(size_t)s * 16 + l];
        acc.x += w * bf2f(u.x);
        acc.y += w * bf2f(u.y);
        acc.z += w * bf2f(u.z);
        acc.w += w * bf2f(u.w);
    }
    acc.x += __shfl_xor(acc.x, 16); acc.x += __shfl_xor(acc.x, 32);
    acc.y += __shfl_xor(acc.y, 16); acc.y += __shfl_xor(acc.y, 32);
    acc.z += __shfl_xor(acc.z, 16); acc.z += __shfl_xor(acc.z, 32);
    acc.w += __shfl_xor(acc.w, 16); acc.w += __shfl_xor(acc.w, 32);
    if (g == 0) {
        float d = dis[node];
        float sc = (POW == 2) ? d * d : d;
        ushort4 o;
        o.x = f2bf(acc.x * sc);
        o.y = f2bf(acc.y * sc);
        o.z = f2bf(acc.z * sc);
        o.w = f2bf(acc.w * sc);
        out4u[(size_t)node * 16 + l] = o;
    }
}

// ---------------- mean-agg over bf16 t1 + selu epilogue, bf16 out ----------------
__global__ __launch_bounds__(256) void prop_mean_bf_kernel(const ushort4* __restrict__ in4u,
                                                           ushort4* __restrict__ out4u,
                                                           const int* __restrict__ row_ptr,
                                                           const int* __restrict__ csr_src,
                                                           const float* __restrict__ cnt_inv,
                                                           const float4* __restrict__ r4,
                                                           const float4* __restrict__ b4,
                                                           int n) {
    int lane = threadIdx.x & 63;
    int g = lane >> 4;
    int l = lane & 15;
    int node = RFL(blockIdx.x * 4 + (threadIdx.x >> 6));
    if (node >= n) return;
    int beg = row_ptr[node];
    int end = row_ptr[node + 1];
    float4 acc = make_float4(0.f, 0.f, 0.f, 0.f);
    int j = beg;
    for (; j + 16 <= end; j += 16) {
        int s[4];
        ushort4 u[4];
#pragma unroll
        for (int q = 0; q < 4; ++q) s[q] = csr_src[j + q * 4 + g];
#pragma unroll
        for (int q = 0; q < 4; ++q) u[q] = in4u[(size_t)s[q] * 16 + l];
#pragma unroll
        for (int q = 0; q < 4; ++q) {
            acc.x += bf2f(u[q].x);
            acc.y += bf2f(u[q].y);
            acc.z += bf2f(u[q].z);
            acc.w += bf2f(u[q].w);
        }
    }
    for (; j + 8 <= end; j += 8) {
        int s[2];
        ushort4 u[2];
#pragma unroll
        for (int q = 0; q < 2; ++q) s[q] = csr_src[j + q * 4 + g];
#pragma unroll
        for (int q = 0; q < 2; ++q) u[q] = in4u[(size_t)s[q] * 16 + l];
#pragma unroll
        for (int q = 0; q < 2; ++q) {
            acc.x += bf2f(u[q].x);
            acc.y += bf2f(u[q].y);
            acc.z += bf2f(u[q].z);
            acc.w += bf2f(u[q].w);
        }
    }
    for (; j < end; j += 4) {
        int idx = j + g;
        bool valid = idx < end;
        int s = csr_src[valid ? idx : (end - 1)];
        float w = valid ? 1.0f : 0.0f;
        ushort4 u = in4u[(size_t)s * 16 + l];
        acc.x += w * bf2f(u.x);
        acc.y += w * bf2f(u.y);
        acc.z += w * bf2f(u.z);
        acc.w += w * bf2f(u.w);
    }
    acc.x += __shfl_xor(acc.x, 16); acc.x += __shfl_xor(acc.x, 32);
    acc.y += __shfl_xor(acc.y, 16); acc.y += __shfl_xor(acc.y, 32);
    acc.z += __shfl_xor(acc.z, 16); acc.z += __shfl_xor(acc.z, 32);
    acc.w += __shfl_xor(acc.w, 16); acc.w += __shfl_xor(acc.w, 32);
    if (g == 0) {
        float sc = cnt_inv[node];
        float4 ra = r4[(size_t)node * 16 + l];
        float4 bb = b4[l];
        const float scale = 1.0507009873554805f;
        const float alpha = 1.6732632423543772f;
        float t0 = acc.x * sc + ra.x + bb.x;
        float t1 = acc.y * sc + ra.y + bb.y;
        float t2 = acc.z * sc + ra.z + bb.z;
        float t3 = acc.w * sc + ra.w + bb.w;
        t0 = scale * (t0 > 0.0f ? t0 : alpha * expm1f(t0));
        t1 = scale * (t1 > 0.0f ? t1 : alpha * expm1f(t1));
        t2 = scale * (t2 > 0.0f ? t2 : alpha * expm1f(t2));
        t3 = scale * (t3 > 0.0f ? t3 : alpha * expm1f(t3));
        ushort4 o;
        o.x = f2bf(t0); o.y = f2bf(t1); o.z = f2bf(t2); o.w = f2bf(t3);
        out4u[(size_t)node * 16 + l] = o;
    }
}

// ---------------- plain mean-agg over bf16 h1, f16 out (agg2) ----------------
__global__ __launch_bounds__(256) void prop_mean_plain_kernel(const ushort4* __restrict__ in4u,
                                                              ushort4* __restrict__ out4u,
                                                              const int* __restrict__ row_ptr,
                                                              const int* __restrict__ csr_src,
                                                              const float* __restrict__ cnt_inv,
                                                              int n) {
    int lane = threadIdx.x & 63;
    int g = lane >> 4;
    int l = lane & 15;
    int node = RFL(blockIdx.x * 4 + (threadIdx.x >> 6));
    if (node >= n) return;
    int beg = row_ptr[node];
    int end = row_ptr[node + 1];
    float4 acc = make_float4(0.f, 0.f, 0.f, 0.f);
    int j = beg;
    for (; j + 16 <= end; j += 16) {
        int s[4];
        ushort4 u[4];
#pragma unroll
        for (int q = 0; q < 4; ++q) s[q] = csr_src[j + q * 4 + g];
#pragma unroll
        for (int q = 0; q < 4; ++q) u[q] = in4u[(size_t)s[q] * 16 + l];
#pragma unroll
        for (int q = 0; q < 4; ++q) {
            acc.x += bf2f(u[q].x);
            acc.y += bf2f(u[q].y);
            acc.z += bf2f(u[q].z);
            acc.w += bf2f(u[q].w);
        }
    }
    for (; j + 8 <= end; j += 8) {
        int s[2];
        ushort4 u[2];
#pragma unroll
        for (int q = 0; q < 2; ++q) s[q] = csr_src[j + q * 4 + g];
#pragma unroll
        for (int q = 0; q < 2; ++q) u[q] = in4u[(size_t)s[q] * 16 + l];
#pragma unroll
        for (int q = 0; q < 2; ++q) {
            acc.x += bf2f(u[q].x);
            acc.y += bf2f(u[q].y);
            acc.z += bf2f(u[q].z);
            acc.w += bf2f(u[q].w);
        }
    }
    for (; j < end; j += 4) {
        int idx = j + g;
        bool valid = idx < end;
        int s = csr_src[valid ? idx : (end - 1)];
        float w = valid ? 1.0f : 0.0f;
        ushort4 u = in4u[(size_t)s * 16 + l];
        acc.x += w * bf2f(u.x);
        acc.y += w * bf2f(u.y);
        acc.z += w * bf2f(u.z);
        acc.w += w * bf2f(u.w);
    }
    acc.x += __shfl_xor(acc.x, 16); acc.x += __shfl_xor(acc.x, 32);
    acc.y += __shfl_xor(acc.y, 16); acc.y += __shfl_xor(acc.y, 32);
    acc.z += __shfl_xor(acc.z, 16); acc.z += __shfl_xor(acc.z, 32);
    acc.w += __shfl_xor(acc.w, 16); acc.w += __shfl_xor(acc.w, 32);
    if (g == 0) {
        float sc = cnt_inv[node];
        ushort4 o;
        o.x = f2h(acc.x * sc);
        o.y = f2h(acc.y * sc);
        o.z = f2h(acc.z * sc);
        o.w = f2h(acc.w * sc);
        out4u[(size_t)node * 16 + l] = o;
    }
}

// ---------------- MFMA GEMM (layer 1): [outL(bf16)|outR(fp32)] = in_bf16(N x 64) @ [Wl|Wr] ----------------
// Block = 64 nodes x OC cols, 4 waves; wave = 16-node band x all OC cols.
// Weights fp32 split into bf16 hi + bf16 residual; both MFMA'd into the same fp32 acc.
// LDS tiles [row][k] bf16, XOR-swizzled: 16B-chunk index kb ^= (row&7).
template <int OC>
__global__ __launch_bounds__(256) void gemm_mfma_kernel(const unsigned short* __restrict__ in,
                                                        const float* __restrict__ Wl,
                                                        const float* __restrict__ Wr,
                                                        const float* __restrict__ bias,
                                                        __hip_bfloat16* __restrict__ outL,
                                                        float* __restrict__ outR,
                                                        int n, int add_bias) {
    constexpr int HC = OC / 2;
    constexpr int NF = OC / 16;          // n-frags per wave
    __shared__ unsigned short sA[64 * 64];        // [m][k] swizzled
    __shared__ unsigned short sBh[OC * 64];       // [c][k] swizzled, hi
    __shared__ unsigned short sBr[OC * 64];       // [c][k] swizzled, residual
    int t = threadIdx.x;
    int blk = blockIdx.x;

    // Stage A: 64 nodes x 64 k bf16, 16B chunks. idx -> m = idx>>3, kb = idx&7.
#pragma unroll
    for (int i = 0; i < 2; ++i) {
        int idx = i * 256 + t;
        int m = idx >> 3;
        int kb = idx & 7;
        int node = blk * 64 + m;
        if (node >= n) node = n - 1;
        ushort8v v = *reinterpret_cast<const ushort8v*>(in + (size_t)node * 64 + kb * 8);
        *reinterpret_cast<ushort8v*>(&sA[m * 64 + ((kb ^ (m & 7)) << 3)]) = v;
    }
    // Stage B: [Wl|Wr] fp32 64k x OC -> bf16 hi/res, transposed to [c][k].
    for (int idx = t; idx < 64 * OC; idx += 256) {
        int k = idx / OC;
        int c = idx - k * OC;
        float v = (c < HC) ? Wl[k * HC + c] : Wr[k * HC + (c - HC)];
        unsigned short hi = f2bf(v);
        unsigned short re = f2bf(v - bf2f(hi));
        int pos = c * 64 + (((k >> 3) ^ (c & 7)) << 3) + (k & 7);
        sBh[pos] = hi;
        sBr[pos] = re;
    }
    __syncthreads();

    int w = t >> 6;          // wave id: m-band [w*16, w*16+16)
    int lane = t & 63;
    int r = lane & 15;
    int q = lane >> 4;       // k-block within MFMA
    int m = w * 16 + r;      // A row for input frags
    // A frags: k-chunks (s*4+q) for MFMA k-step s
    bf16x8 A0 = *reinterpret_cast<const bf16x8*>(&sA[m * 64 + (((0 + q) ^ (r & 7)) << 3)]);
    bf16x8 A1 = *reinterpret_cast<const bf16x8*>(&sA[m * 64 + (((4 + q) ^ (r & 7)) << 3)]);

    f32x4 acc[NF];
#pragma unroll
    for (int c = 0; c < NF; ++c) acc[c] = (f32x4)(0.0f);

#pragma unroll
    for (int c = 0; c < NF; ++c) {
        int cb = c * 16 + r;
        bf16x8 B0 = *reinterpret_cast<const bf16x8*>(&sBh[cb * 64 + (((0 + q) ^ (r & 7)) << 3)]);
        bf16x8 B1 = *reinterpret_cast<const bf16x8*>(&sBh[cb * 64 + (((4 + q) ^ (r & 7)) << 3)]);
        bf16x8 R0 = *reinterpret_cast<const bf16x8*>(&sBr[cb * 64 + (((0 + q) ^ (r & 7)) << 3)]);
        bf16x8 R1 = *reinterpret_cast<const bf16x8*>(&sBr[cb * 64 + (((4 + q) ^ (r & 7)) << 3)]);
        acc[c] = __builtin_amdgcn_mfma_f32_16x16x32_bf16(A0, B0, acc[c], 0, 0, 0);
        acc[c] = __builtin_amdgcn_mfma_f32_16x16x32_bf16(A1, B1, acc[c], 0, 0, 0);
        acc[c] = __builtin_amdgcn_mfma_f32_16x16x32_bf16(A0, R0, acc[c], 0, 0, 0);
        acc[c] = __builtin_amdgcn_mfma_f32_16x16x32_bf16(A1, R1, acc[c], 0, 0, 0);
    }

    // Epilogue: C/D frag: col = c*16 + (lane&15), row = (lane>>4)*4 + j (within wave's band).
#pragma unroll
    for (int c = 0; c < NF; ++c) {
        int col = c * 16 + r;
#pragma unroll
        for (int j = 0; j < 4; ++j) {
            int node = blk * 64 + w * 16 + q * 4 + j;
            if (node < n) {
                float v = acc[c][j];
                if (col < HC) {
                    outL[(size_t)node * HC + col] = __float2bfloat16(v);
                } else {
                    outR[(size_t)node * HC + (col - HC)] = v + (add_bias ? bias[col - HC] : 0.0f);
                }
            }
        }
    }
}

// ---------------- fused layer-2 GEMM + softmax ----------------
// out = softmax([agg2(f16)|h1(bf16)] @ [Wl2;Wr2] + b2), k=128, 40 cols (padded to 48).
// Block = 64 nodes, 4 waves; wave = 16-node band x 48 cols (3 frags).
__global__ __launch_bounds__(256) void gemm2_softmax_kernel(const unsigned short* __restrict__ aggf,
                                                            const unsigned short* __restrict__ h1,
                                                            const float* __restrict__ Wl2,
                                                            const float* __restrict__ Wr2,
                                                            const float* __restrict__ b2,
                                                            float* __restrict__ out,
                                                            int n) {
    __shared__ unsigned short sA[64 * 128];       // [m][k] swizzled: k<64 f16 agg2, k>=64 bf16 h1
    __shared__ unsigned short sBh[48 * 128];      // [c][k] swizzled, hi
    __shared__ unsigned short sBr[48 * 128];      // [c][k] swizzled, residual
    int t = threadIdx.x;
    int blk = blockIdx.x;

    // Stage A: 64 rows x 16 chunks of 16B.
#pragma unroll
    for (int i = 0; i < 4; ++i) {
        int idx = i * 256 + t;
        int m = idx >> 4;
        int kb = idx & 15;
        int node = blk * 64 + m;
        if (node >= n) node = n - 1;
        const unsigned short* srcp = (kb < 8) ? aggf : h1;
        ushort8v v = *reinterpret_cast<const ushort8v*>(srcp + (size_t)node * 64 + (kb & 7) * 8);
        *reinterpret_cast<ushort8v*>(&sA[m * 128 + ((kb ^ (m & 7)) << 3)]) = v;
    }
    // Stage B: 48 cols x 128 k. k<64: f16 split of Wl2; k>=64: bf16 split of Wr2. cols>=40 zero.
    for (int idx = t; idx < 48 * 128; idx += 256) {
        int k = idx / 48;
        int c = idx - k * 48;
        float v = 0.0f;
        if (c < 40) v = (k < 64) ? Wl2[k * 40 + c] : Wr2[(k - 64) * 40 + c];
        unsigned short hi, re;
        if (k < 64) {
            _Float16 h = (_Float16)v;
            float res = v - (float)h;
            _Float16 h2 = (_Float16)res;
            hi = *reinterpret_cast<unsigned short*>(&h);
            re = *reinterpret_cast<unsigned short*>(&h2);
        } else {
            hi = f2bf(v);
            re = f2bf(v - bf2f(hi));
        }
        int pos = c * 128 + (((k >> 3) ^ (c & 7)) << 3) + (k & 7);
        sBh[pos] = hi;
        sBr[pos] = re;
    }
    __syncthreads();

    int w = t >> 6;
    int lane = t & 63;
    int r = lane & 15;
    int q = lane >> 4;
    int m = w * 16 + r;
    // A frags: k-step s covers chunks s*4+q. s=0,1 -> f16 (agg2); s=2,3 -> bf16 (h1).
    f16x8  Af0 = *reinterpret_cast<const f16x8*>(&sA[m * 128 + (((0 + q) ^ (r & 7)) << 3)]);
    f16x8  Af1 = *reinterpret_cast<const f16x8*>(&sA[m * 128 + (((4 + q) ^ (r & 7)) << 3)]);
    bf16x8 Ab0 = *reinterpret_cast<const bf16x8*>(&sA[m * 128 + (((8 + q) ^ (r & 7)) << 3)]);
    bf16x8 Ab1 = *reinterpret_cast<const bf16x8*>(&sA[m * 128 + (((12 + q) ^ (r & 7)) << 3)]);

    f32x4 acc[3];
#pragma unroll
    for (int c = 0; c < 3; ++c) acc[c] = (f32x4)(0.0f);

#pragma unroll
    for (int c = 0; c < 3; ++c) {
        int cb = c * 16 + r;
        const unsigned short* bh = &sBh[cb * 128];
        const unsigned short* br = &sBr[cb * 128];
        f16x8  Bf0 = *reinterpret_cast<const f16x8*>(&bh[(((0 + q) ^ (r & 7)) << 3)]);
        f16x8  Bf1 = *reinterpret_cast<const f16x8*>(&bh[(((4 + q) ^ (r & 7)) << 3)]);
        bf16x8 Bb0 = *reinterpret_cast<const bf16x8*>(&bh[(((8 + q) ^ (r & 7)) << 3)]);
        bf16x8 Bb1 = *reinterpret_cast<const bf16x8*>(&bh[(((12 + q) ^ (r & 7)) << 3)]);
        f16x8  Rf0 = *reinterpret_cast<const f16x8*>(&br[(((0 + q) ^ (r & 7)) << 3)]);
        f16x8  Rf1 = *reinterpret_cast<const f16x8*>(&br[(((4 + q) ^ (r & 7)) << 3)]);
        bf16x8 Rb0 = *reinterpret_cast<const bf16x8*>(&br[(((8 + q) ^ (r & 7)) << 3)]);
        bf16x8 Rb1 = *reinterpret_cast<const bf16x8*>(&br[(((12 + q) ^ (r & 7)) << 3)]);
        acc[c] = __builtin_amdgcn_mfma_f32_16x16x32_f16(Af0, Bf0, acc[c], 0, 0, 0);
        acc[c] = __builtin_amdgcn_mfma_f32_16x16x32_f16(Af1, Bf1, acc[c], 0, 0, 0);
        acc[c] = __builtin_amdgcn_mfma_f32_16x16x32_f16(Af0, Rf0, acc[c], 0, 0, 0);
        acc[c] = __builtin_amdgcn_mfma_f32_16x16x32_f16(Af1, Rf1, acc[c], 0, 0, 0);
        acc[c] = __builtin_amdgcn_mfma_f32_16x16x32_bf16(Ab0, Bb0, acc[c], 0, 0, 0);
        acc[c] = __builtin_amdgcn_mfma_f32_16x16x32_bf16(Ab1, Bb1, acc[c], 0, 0, 0);
        acc[c] = __builtin_amdgcn_mfma_f32_16x16x32_bf16(Ab0, Rb0, acc[c], 0, 0, 0);
        acc[c] = __builtin_amdgcn_mfma_f32_16x16x32_bf16(Ab1, Rb1, acc[c], 0, 0, 0);
    }

    // Softmax epilogue. Row = w*16 + q*4 + j; cols = {r, 16+r, 32+r(<40 iff r<8)}.
    float bv0 = b2[r];
    float bv1 = b2[16 + r];
    float bv2 = (r < 8) ? b2[32 + r] : 0.0f;
#pragma unroll
    for (int j = 0; j < 4; ++j) {
        int node = blk * 64 + w * 16 + q * 4 + j;
        float v0 = acc[0][j] + bv0;
        float v1 = acc[1][j] + bv1;
        float v2 = (r < 8) ? (acc[2][j] + bv2) : -INFINITY;
        float mx = fmaxf(fmaxf(v0, v1), v2);
        mx = fmaxf(mx, __shfl_xor(mx, 1));
        mx = fmaxf(mx, __shfl_xor(mx, 2));
        mx = fmaxf(mx, __shfl_xor(mx, 4));
        mx = fmaxf(mx, __shfl_xor(mx, 8));
        float e0 = __expf(v0 - mx);
        float e1 = __expf(v1 - mx);
        float e2 = (r < 8) ? __expf(v2 - mx) : 0.0f;
        float s = e0 + e1 + e2;
        s += __shfl_xor(s, 1);
        s += __shfl_xor(s, 2);
        s += __shfl_xor(s, 4);
        s += __shfl_xor(s, 8);
        if (node < n) {
            float inv = 1.0f / s;
            out[(size_t)node * 40 + r] = e0 * inv;
            out[(size_t)node * 40 + 16 + r] = e1 * inv;
            if (r < 8) out[(size_t)node * 40 + 32 + r] = e2 * inv;
        }
    }
}

// ---------------- launch ----------------

extern "C" void kernel_launch(void* const* d_in, const int* in_sizes, int n_in,
                              void* d_out, int out_size, void* d_ws, size_t ws_size,
                              hipStream_t stream) {
    const float* x   = (const float*)d_in[0];
    const float* Wl1 = (const float*)d_in[1];
    const float* Wr1 = (const float*)d_in[2];
    const float* b1  = (const float*)d_in[3];
    const float* Wl2 = (const float*)d_in[4];
    const float* Wr2 = (const float*)d_in[5];
    const float* b2  = (const float*)d_in[6];
    const int* edge_src = (const int*)d_in[7];
    const int* edge_dst = (const int*)d_in[8];
    float* out = (float*)d_out;

    const int N = in_sizes[0] / 64;
    const int E = in_sizes[7];
    const int NBUCK = (N + (1 << BK_SHIFT) - 1) >> BK_SHIFT;   // 98
    size_t buf_bytes = (size_t)N * 64 * 4;
    int cap = E / NBUCK + E / (2 * NBUCK) + 1024;              // mean + 50% + slack
    int cap_max = (int)(buf_bytes / ((size_t)NBUCK * 4));
    if (cap > cap_max) cap = cap_max;

    size_t off = 0;
    auto carve = [&](size_t bytes) -> void* {
        void* p = (char*)d_ws + off;
        off = (off + bytes + 255) & ~(size_t)255;
        return p;
    };
    int*          row_ptr = (int*)carve((size_t)(N + 1) * 4);
    int*          bcursor = (int*)carve((size_t)NBUCK * 4);
    float*        dis     = (float*)carve((size_t)N * 4);
    float*        cnt_inv = (float*)carve((size_t)N * 4);
    int*          csr_src = (int*)carve((size_t)E * 4);
    char*         bufA    = (char*)carve(buf_bytes);
    char*         bufB    = (char*)carve(buf_bytes);
    float*        bufC    = (float*)carve(buf_bytes);          // temp / r1
    unsigned int* temp    = (unsigned int*)bufC;               // dead before r1 written
    (void)ws_size;

    // bf16/f16 sub-buffers (sequenced so nothing live overlaps):
    unsigned short* xb    = (unsigned short*)bufA;                       // x' = dis*x bf16
    unsigned short* p0b   = (unsigned short*)(bufA + buf_bytes / 2);     // p0' bf16
    unsigned short* hb    = (unsigned short*)bufB;                       // h bf16
    unsigned short* t1b   = (unsigned short*)bufA;                       // t1 bf16 (xb dead)
    unsigned short* h1b   = (unsigned short*)bufB;                       // h1 bf16 (hb dead)
    unsigned short* agg2b = (unsigned short*)(bufA + buf_bytes / 2);     // agg2 f16 (p0b dead)

    const int nb_node = (N + 3) / 4;
    const int nb_gemm = (N + 63) / 64;
    const int n4 = N * 64 / 4;

    // CSR build (bcursor zeroed via async memset; partition uses relative cursors)
    hipMemsetAsync(bcursor, 0, (size_t)NBUCK * 4, stream);
    partition_kernel<<<256, 256, 0, stream>>>(edge_src, edge_dst, bcursor, temp, E, NBUCK, cap);
    bucket_csr_kernel<<<NBUCK, 256, 0, stream>>>(temp, bcursor, row_ptr, dis, cnt_inv,
                                                 csr_src, N, cap, NBUCK, E);

    // x' = bf16(dis * x)   (pre-scaled KProp input; needs dis, so after bucket_csr)
    f2bf_scale_kernel<<<(n4 + 255) / 256, 256, 0, stream>>>((const float4*)x, (ushort4*)xb,
                                                            dis, n4);
    // KProp x2 (pre-scaled): p0' = dis^2 * sum x'[s] ; h = dis * sum p0'[s]
    prop4bf_kernel<2><<<nb_node, 256, 0, stream>>>((const ushort4*)xb, (ushort4*)p0b,
                                                   row_ptr, csr_src, dis, N);
    prop4bf_kernel<1><<<nb_node, 256, 0, stream>>>((const ushort4*)p0b, (ushort4*)hb,
                                                   row_ptr, csr_src, dis, N);
    // [t1(bf16)|r1(fp32)] = h @ [Wl1|Wr1]  (MFMA)
    gemm_mfma_kernel<128><<<nb_gemm, 256, 0, stream>>>(hb, Wl1, Wr1, nullptr,
                                                       (__hip_bfloat16*)t1b, bufC, N, 0);
    // h1 = selu(mean(t1) + r1 + b1) -> bf16
    prop_mean_bf_kernel<<<nb_node, 256, 0, stream>>>((const ushort4*)t1b, (ushort4*)h1b,
                                                     row_ptr, csr_src, cnt_inv,
                                                     (const float4*)bufC, (const float4*)b1, N);
    // agg2 = mean(h1) -> f16
    prop_mean_plain_kernel<<<nb_node, 256, 0, stream>>>((const ushort4*)h1b, (ushort4*)agg2b,
                                                        row_ptr, csr_src, cnt_inv, N);
    // out = softmax([agg2|h1] @ [Wl2;Wr2] + b2)
    gemm2_softmax_kernel<<<nb_gemm, 256, 0, stream>>>(agg2b, h1b, Wl2, Wr2, b2, out, N);
}

// Round 6
// 366.838 us; speedup vs baseline: 1.1863x; 1.0090x over previous
//
#include <hip/hip_runtime.h>
#include <hip/hip_bf16.h>
#include <math.h>

// Node classifier: KProp(K=2, gcn_norm) -> SAGEConv(64->64)+selu -> SAGEConv(64->40) -> softmax
// N=100000, E=1600000, D=H=64, C=40.
//
// R18 = R17 with layer 1 restructured like layer 2 (mean commutes with linear map):
//   hm  = mean-gather(h)   (plain mean, f16 out)
//   h1  = selu([hm|h] @ [Wl1;Wr1] + b1)   fused MFMA GEMM (replaces gemm1 + prop_mean_bf)
//   Kills the r1 fp32 round-trip (51 MB) and the epilogue-streamed mean kernel.
//   Both layers now use the identical gather->fused-GEMM structure.

#define RFL(x) __builtin_amdgcn_readfirstlane(x)
#define BK_SHIFT 10        // coarse bucket = dst>>10 (1024 nodes)
#define MAXBUCK 256

typedef short bf16x8 __attribute__((ext_vector_type(8)));
typedef _Float16 f16x8 __attribute__((ext_vector_type(8)));
typedef float f32x4 __attribute__((ext_vector_type(4)));
typedef unsigned short ushort8v __attribute__((ext_vector_type(8)));

__device__ __forceinline__ float bf2f(unsigned short u) {
    return __uint_as_float((unsigned)u << 16);
}
__device__ __forceinline__ unsigned short f2bf(float f) {
    __hip_bfloat16 b = __float2bfloat16(f);   // RTN
    return *reinterpret_cast<unsigned short*>(&b);
}
__device__ __forceinline__ unsigned short f2h(float f) {
    _Float16 h = (_Float16)f;                 // RTN
    return *reinterpret_cast<unsigned short*>(&h);
}

// ---------------- CSR build ----------------

// Phase 1: block-private coarse bucket partition; packed u32 (src<<10 | dst&1023).
// bcursor[] starts at 0 (memset); holds per-bucket relative fill count.
__global__ __launch_bounds__(256) void partition_kernel(const int* __restrict__ src,
                                                        const int* __restrict__ dst,
                                                        int* __restrict__ bcursor,
                                                        unsigned int* __restrict__ temp,
                                                        int e, int nbuck, int cap) {
    __shared__ int bc[MAXBUCK];
    int t = threadIdx.x;
    int chunk = (e + gridDim.x - 1) / gridDim.x;
    int base = blockIdx.x * chunk;
    int cnt = e - base;
    if (cnt > chunk) cnt = chunk;
    if (cnt < 0) cnt = 0;
    for (int j = t; j < nbuck; j += 256) bc[j] = 0;
    __syncthreads();
    for (int i = t; i < cnt; i += 256) {
        int d = dst[base + i];
        atomicAdd(&bc[d >> BK_SHIFT], 1);
    }
    __syncthreads();
    for (int j = t; j < nbuck; j += 256) {
        int c = bc[j];
        bc[j] = (c > 0) ? (atomicAdd(&bcursor[j], c) + j * cap) : 0;
    }
    __syncthreads();
    for (int i = t; i < cnt; i += 256) {
        int s = src[base + i];
        int d = dst[base + i];
        int bk = d >> BK_SHIFT;
        int p = atomicAdd(&bc[bk], 1);
        if (p < (bk + 1) * cap) temp[p] = ((unsigned int)s << BK_SHIFT) | (unsigned int)(d & 1023);
    }
}

// Phase 2: per-bucket counting sort by node_local + deg/dis/cnt_inv/row_ptr.
__global__ __launch_bounds__(256) void bucket_csr_kernel(const unsigned int* __restrict__ temp,
                                                         const int* __restrict__ bcursor,
                                                         int* __restrict__ row_ptr,
                                                         float* __restrict__ dis,
                                                         float* __restrict__ cnt_inv,
                                                         int* __restrict__ csr_src,
                                                         int n, int cap, int nbuck, int e) {
    __shared__ int cnt3[1024];
    __shared__ int part[256];
    int b = blockIdx.x;
    int t = threadIdx.x;
    int nbeg = b << BK_SHIFT;
    int cj = 0;
    if (t < nbuck) {
        cj = bcursor[t];
        if (cj > cap) cj = cap;
    }
    part[t] = cj;
    __syncthreads();
    for (int off = 1; off < 256; off <<= 1) {
        int u = (t >= off) ? part[t - off] : 0;
        __syncthreads();
        part[t] += u;
        __syncthreads();
    }
    int cntb = bcursor[b];
    if (cntb > cap) cntb = cap;
    int bbase = part[b] - cntb;
    __syncthreads();
    for (int i = t; i < 1024; i += 256) cnt3[i] = 0;
    __syncthreads();
    const unsigned int* tb = temp + (size_t)b * cap;
    for (int i = t; i < cntb; i += 256) {
        atomicAdd(&cnt3[tb[i] & 1023u], 1);
    }
    __syncthreads();
    int d0 = cnt3[t * 4 + 0], d1 = cnt3[t * 4 + 1], d2 = cnt3[t * 4 + 2], d3 = cnt3[t * 4 + 3];
    int run = d0 + d1 + d2 + d3;
    int dd[4] = {d0, d1, d2, d3};
#pragma unroll
    for (int k = 0; k < 4; ++k) {
        int node = nbeg + t * 4 + k;
        if (node < n) {
            float fd = (float)dd[k];
            dis[node] = (dd[k] > 0) ? rsqrtf(fd) : 0.0f;
            cnt_inv[node] = 1.0f / fmaxf(fd, 1.0f);
        }
    }
    __syncthreads();
    part[t] = run;
    __syncthreads();
    for (int off = 1; off < 256; off <<= 1) {
        int u = (t >= off) ? part[t - off] : 0;
        __syncthreads();
        part[t] += u;
        __syncthreads();
    }
    int ex = part[t] - run;
    int oo[4];
    oo[0] = ex; oo[1] = ex + d0; oo[2] = ex + d0 + d1; oo[3] = ex + d0 + d1 + d2;
#pragma unroll
    for (int k = 0; k < 4; ++k) {
        cnt3[t * 4 + k] = oo[k];
        int node = nbeg + t * 4 + k;
        if (node < n) row_ptr[node] = bbase + oo[k];
    }
    if (b == nbuck - 1 && t == 0) row_ptr[n] = e;
    __syncthreads();
    for (int i = t; i < cntb; i += 256) {
        unsigned int ed = tb[i];
        int pos = atomicAdd(&cnt3[ed & 1023u], 1);
        csr_src[bbase + pos] = (int)(ed >> BK_SHIFT);
    }
}

// ---------------- fp32 -> bf16 convert, pre-scaled by dis[node] ----------------
__global__ void f2bf_scale_kernel(const float4* __restrict__ in, ushort4* __restrict__ out,
                                  const float* __restrict__ dis, int n4) {
    int i = blockIdx.x * blockDim.x + threadIdx.x;
    if (i < n4) {
        float d = dis[i >> 4];
        float4 v = in[i];
        ushort4 u;
        u.x = f2bf(v.x * d); u.y = f2bf(v.y * d); u.z = f2bf(v.z * d); u.w = f2bf(v.w * d);
        out[i] = u;
    }
}

// ---------------- KProp propagation: unweighted row-sum, final scale dis^POW ----------------
// Wave per node. lane = g*16 + l: edge slot g (0..3), feature quad l (0..15).
// POW==2: out = dis^2 * sum (round 1, input pre-scaled x'); POW==1: out = dis * sum (round 2).
template <int POW>
__global__ __launch_bounds__(256) void prop4bf_kernel(const ushort4* __restrict__ in4u,
                                                      ushort4* __restrict__ out4u,
                                                      const int* __restrict__ row_ptr,
                                                      const int* __restrict__ csr_src,
                                                      const float* __restrict__ dis,
                                                      int n) {
    int lane = threadIdx.x & 63;
    int g = lane >> 4;
    int l = lane & 15;
    int node = RFL(blockIdx.x * 4 + (threadIdx.x >> 6));
    if (node >= n) return;
    int beg = row_ptr[node];
    int end = row_ptr[node + 1];
    float4 acc = make_float4(0.f, 0.f, 0.f, 0.f);
    int j = beg;
    for (; j + 16 <= end; j += 16) {
        int s[4];
        ushort4 u[4];
#pragma unroll
        for (int q = 0; q < 4; ++q) s[q] = csr_src[j + q * 4 + g];
#pragma unroll
        for (int q = 0; q < 4; ++q) u[q] = in4u[(size_t)s[q] * 16 + l];
#pragma unroll
        for (int q = 0; q < 4; ++q) {
            acc.x += bf2f(u[q].x);
            acc.y += bf2f(u[q].y);
            acc.z += bf2f(u[q].z);
            acc.w += bf2f(u[q].w);
        }
    }
    for (; j + 8 <= end; j += 8) {
        int s[2];
        ushort4 u[2];
#pragma unroll
        for (int q = 0; q < 2; ++q) s[q] = csr_src[j + q * 4 + g];
#pragma unroll
        for (int q = 0; q < 2; ++q) u[q] = in4u[(size_t)s[q] * 16 + l];
#pragma unroll
        for (int q = 0; q < 2; ++q) {
            acc.x += bf2f(u[q].x);
            acc.y += bf2f(u[q].y);
            acc.z += bf2f(u[q].z);
            acc.w += bf2f(u[q].w);
        }
    }
    for (; j < end; j += 4) {
        int idx = j + g;
        bool valid = idx < end;
        int s = csr_src[valid ? idx : (end - 1)];
        float w = valid ? 1.0f : 0.0f;
        ushort4 u = in4u[(size_t)s * 16 + l];
        acc.x += w * bf2f(u.x);
        acc.y += w * bf2f(u.y);
        acc.z += w * bf2f(u.z);
        acc.w += w * bf2f(u.w);
    }
    acc.x += __shfl_xor(acc.x, 16); acc.x += __shfl_xor(acc.x, 32);
    acc.y += __shfl_xor(acc.y, 16); acc.y += __shfl_xor(acc.y, 32);
    acc.z += __shfl_xor(acc.z, 16); acc.z += __shfl_xor(acc.z, 32);
    acc.w += __shfl_xor(acc.w, 16); acc.w += __shfl_xor(acc.w, 32);
    if (g == 0) {
        float d = dis[node];
        float sc = (POW == 2) ? d * d : d;
        ushort4 o;
        o.x = f2bf(acc.x * sc);
        o.y = f2bf(acc.y * sc);
        o.z = f2bf(acc.z * sc);
        o.w = f2bf(acc.w * sc);
        out4u[(size_t)node * 16 + l] = o;
    }
}

// ---------------- plain mean-agg over bf16 rows, f16 out ----------------
__global__ __launch_bounds__(256) void prop_mean_plain_kernel(const ushort4* __restrict__ in4u,
                                                              ushort4* __restrict__ out4u,
                                                              const int* __restrict__ row_ptr,
                                                              const int* __restrict__ csr_src,
                                                              const float* __restrict__ cnt_inv,
                                                              int n) {
    int lane = threadIdx.x & 63;
    int g = lane >> 4;
    int l = lane & 15;
    int node = RFL(blockIdx.x * 4 + (threadIdx.x >> 6));
    if (node >= n) return;
    int beg = row_ptr[node];
    int end = row_ptr[node + 1];
    float4 acc = make_float4(0.f, 0.f, 0.f, 0.f);
    int j = beg;
    for (; j + 16 <= end; j += 16) {
        int s[4];
        ushort4 u[4];
#pragma unroll
        for (int q = 0; q < 4; ++q) s[q] = csr_src[j + q * 4 + g];
#pragma unroll
        for (int q = 0; q < 4; ++q) u[q] = in4u[(size_t)s[q] * 16 + l];
#pragma unroll
        for (int q = 0; q < 4; ++q) {
            acc.x += bf2f(u[q].x);
            acc.y += bf2f(u[q].y);
            acc.z += bf2f(u[q].z);
            acc.w += bf2f(u[q].w);
        }
    }
    for (; j + 8 <= end; j += 8) {
        int s[2];
        ushort4 u[2];
#pragma unroll
        for (int q = 0; q < 2; ++q) s[q] = csr_src[j + q * 4 + g];
#pragma unroll
        for (int q = 0; q < 2; ++q) u[q] = in4u[(size_t)s[q] * 16 + l];
#pragma unroll
        for (int q = 0; q < 2; ++q) {
            acc.x += bf2f(u[q].x);
            acc.y += bf2f(u[q].y);
            acc.z += bf2f(u[q].z);
            acc.w += bf2f(u[q].w);
        }
    }
    for (; j < end; j += 4) {
        int idx = j + g;
        bool valid = idx < end;
        int s = csr_src[valid ? idx : (end - 1)];
        float w = valid ? 1.0f : 0.0f;
        ushort4 u = in4u[(size_t)s * 16 + l];
        acc.x += w * bf2f(u.x);
        acc.y += w * bf2f(u.y);
        acc.z += w * bf2f(u.z);
        acc.w += w * bf2f(u.w);
    }
    acc.x += __shfl_xor(acc.x, 16); acc.x += __shfl_xor(acc.x, 32);
    acc.y += __shfl_xor(acc.y, 16); acc.y += __shfl_xor(acc.y, 32);
    acc.z += __shfl_xor(acc.z, 16); acc.z += __shfl_xor(acc.z, 32);
    acc.w += __shfl_xor(acc.w, 16); acc.w += __shfl_xor(acc.w, 32);
    if (g == 0) {
        float sc = cnt_inv[node];
        ushort4 o;
        o.x = f2h(acc.x * sc);
        o.y = f2h(acc.y * sc);
        o.z = f2h(acc.z * sc);
        o.w = f2h(acc.w * sc);
        out4u[(size_t)node * 16 + l] = o;
    }
}

// ---------------- fused layer-1 GEMM + selu ----------------
// h1 = selu([hm(f16)|h(bf16)] @ [Wl1;Wr1] + b1), k=128, 64 cols, bf16 out.
// Block = 64 nodes, 4 waves; wave = 16-node band x 64 cols (4 frags).
__global__ __launch_bounds__(256) void gemm1_selu_kernel(const unsigned short* __restrict__ aggf,
                                                         const unsigned short* __restrict__ h,
                                                         const float* __restrict__ Wl1,
                                                         const float* __restrict__ Wr1,
                                                         const float* __restrict__ b1,
                                                         unsigned short* __restrict__ h1,
                                                         int n) {
    __shared__ unsigned short sA[64 * 128];       // [m][k] swizzled: k<64 f16 hm, k>=64 bf16 h
    __shared__ unsigned short sBh[64 * 128];      // [c][k] swizzled, hi
    __shared__ unsigned short sBr[64 * 128];      // [c][k] swizzled, residual
    int t = threadIdx.x;
    int blk = blockIdx.x;

    // Stage A: 64 rows x 16 chunks of 16B.
#pragma unroll
    for (int i = 0; i < 4; ++i) {
        int idx = i * 256 + t;
        int m = idx >> 4;
        int kb = idx & 15;
        int node = blk * 64 + m;
        if (node >= n) node = n - 1;
        const unsigned short* srcp = (kb < 8) ? aggf : h;
        ushort8v v = *reinterpret_cast<const ushort8v*>(srcp + (size_t)node * 64 + (kb & 7) * 8);
        *reinterpret_cast<ushort8v*>(&sA[m * 128 + ((kb ^ (m & 7)) << 3)]) = v;
    }
    // Stage B: 64 cols x 128 k. k<64: f16 split of Wl1; k>=64: bf16 split of Wr1.
    for (int idx = t; idx < 64 * 128; idx += 256) {
        int k = idx >> 6;
        int c = idx & 63;
        float v = (k < 64) ? Wl1[k * 64 + c] : Wr1[(k - 64) * 64 + c];
        unsigned short hi, re;
        if (k < 64) {
            _Float16 hh = (_Float16)v;
            float res = v - (float)hh;
            _Float16 h2 = (_Float16)res;
            hi = *reinterpret_cast<unsigned short*>(&hh);
            re = *reinterpret_cast<unsigned short*>(&h2);
        } else {
            hi = f2bf(v);
            re = f2bf(v - bf2f(hi));
        }
        int pos = c * 128 + (((k >> 3) ^ (c & 7)) << 3) + (k & 7);
        sBh[pos] = hi;
        sBr[pos] = re;
    }
    __syncthreads();

    int w = t >> 6;
    int lane = t & 63;
    int r = lane & 15;
    int q = lane >> 4;
    int m = w * 16 + r;
    // A frags: k-step s covers chunks s*4+q. s=0,1 -> f16 (hm); s=2,3 -> bf16 (h).
    f16x8  Af0 = *reinterpret_cast<const f16x8*>(&sA[m * 128 + (((0 + q) ^ (r & 7)) << 3)]);
    f16x8  Af1 = *reinterpret_cast<const f16x8*>(&sA[m * 128 + (((4 + q) ^ (r & 7)) << 3)]);
    bf16x8 Ab0 = *reinterpret_cast<const bf16x8*>(&sA[m * 128 + (((8 + q) ^ (r & 7)) << 3)]);
    bf16x8 Ab1 = *reinterpret_cast<const bf16x8*>(&sA[m * 128 + (((12 + q) ^ (r & 7)) << 3)]);

    f32x4 acc[4];
#pragma unroll
    for (int c = 0; c < 4; ++c) acc[c] = (f32x4)(0.0f);

#pragma unroll
    for (int c = 0; c < 4; ++c) {
        int cb = c * 16 + r;
        const unsigned short* bh = &sBh[cb * 128];
        const unsigned short* br = &sBr[cb * 128];
        f16x8  Bf0 = *reinterpret_cast<const f16x8*>(&bh[(((0 + q) ^ (r & 7)) << 3)]);
        f16x8  Bf1 = *reinterpret_cast<const f16x8*>(&bh[(((4 + q) ^ (r & 7)) << 3)]);
        bf16x8 Bb0 = *reinterpret_cast<const bf16x8*>(&bh[(((8 + q) ^ (r & 7)) << 3)]);
        bf16x8 Bb1 = *reinterpret_cast<const bf16x8*>(&bh[(((12 + q) ^ (r & 7)) << 3)]);
        f16x8  Rf0 = *reinterpret_cast<const f16x8*>(&br[(((0 + q) ^ (r & 7)) << 3)]);
        f16x8  Rf1 = *reinterpret_cast<const f16x8*>(&br[(((4 + q) ^ (r & 7)) << 3)]);
        bf16x8 Rb0 = *reinterpret_cast<const bf16x8*>(&br[(((8 + q) ^ (r & 7)) << 3)]);
        bf16x8 Rb1 = *reinterpret_cast<const bf16x8*>(&br[(((12 + q) ^ (r & 7)) << 3)]);
        acc[c] = __builtin_amdgcn_mfma_f32_16x16x32_f16(Af0, Bf0, acc[c], 0, 0, 0);
        acc[c] = __builtin_amdgcn_mfma_f32_16x16x32_f16(Af1, Bf1, acc[c], 0, 0, 0);
        acc[c] = __builtin_amdgcn_mfma_f32_16x16x32_f16(Af0, Rf0, acc[c], 0, 0, 0);
        acc[c] = __builtin_amdgcn_mfma_f32_16x16x32_f16(Af1, Rf1, acc[c], 0, 0, 0);
        acc[c] = __builtin_amdgcn_mfma_f32_16x16x32_bf16(Ab0, Bb0, acc[c], 0, 0, 0);
        acc[c] = __builtin_amdgcn_mfma_f32_16x16x32_bf16(Ab1, Bb1, acc[c], 0, 0, 0);
        acc[c] = __builtin_amdgcn_mfma_f32_16x16x32_bf16(Ab0, Rb0, acc[c], 0, 0, 0);
        acc[c] = __builtin_amdgcn_mfma_f32_16x16x32_bf16(Ab1, Rb1, acc[c], 0, 0, 0);
    }

    // Selu epilogue. Row = w*16 + q*4 + j; col = c*16 + r.
    const float scale = 1.0507009873554805f;
    const float alpha = 1.6732632423543772f;
#pragma unroll
    for (int c = 0; c < 4; ++c) {
        int col = c * 16 + r;
        float bv = b1[col];
#pragma unroll
        for (int j = 0; j < 4; ++j) {
            int node = blk * 64 + w * 16 + q * 4 + j;
            if (node < n) {
                float v = acc[c][j] + bv;
                v = scale * (v > 0.0f ? v : alpha * expm1f(v));
                h1[(size_t)node * 64 + col] = f2bf(v);
            }
        }
    }
}

// ---------------- fused layer-2 GEMM + softmax ----------------
// out = softmax([agg2(f16)|h1(bf16)] @ [Wl2;Wr2] + b2), k=128, 40 cols (padded to 48).
// Block = 64 nodes, 4 waves; wave = 16-node band x 48 cols (3 frags).
__global__ __launch_bounds__(256) void gemm2_softmax_kernel(const unsigned short* __restrict__ aggf,
                                                            const unsigned short* __restrict__ h1,
                                                            const float* __restrict__ Wl2,
                                                            const float* __restrict__ Wr2,
                                                            const float* __restrict__ b2,
                                                            float* __restrict__ out,
                                                            int n) {
    __shared__ unsigned short sA[64 * 128];       // [m][k] swizzled: k<64 f16 agg2, k>=64 bf16 h1
    __shared__ unsigned short sBh[48 * 128];      // [c][k] swizzled, hi
    __shared__ unsigned short sBr[48 * 128];      // [c][k] swizzled, residual
    int t = threadIdx.x;
    int blk = blockIdx.x;

    // Stage A: 64 rows x 16 chunks of 16B.
#pragma unroll
    for (int i = 0; i < 4; ++i) {
        int idx = i * 256 + t;
        int m = idx >> 4;
        int kb = idx & 15;
        int node = blk * 64 + m;
        if (node >= n) node = n - 1;
        const unsigned short* srcp = (kb < 8) ? aggf : h1;
        ushort8v v = *reinterpret_cast<const ushort8v*>(srcp + (size_t)node * 64 + (kb & 7) * 8);
        *reinterpret_cast<ushort8v*>(&sA[m * 128 + ((kb ^ (m & 7)) << 3)]) = v;
    }
    // Stage B: 48 cols x 128 k. k<64: f16 split of Wl2; k>=64: bf16 split of Wr2. cols>=40 zero.
    for (int idx = t; idx < 48 * 128; idx += 256) {
        int k = idx / 48;
        int c = idx - k * 48;
        float v = 0.0f;
        if (c < 40) v = (k < 64) ? Wl2[k * 40 + c] : Wr2[(k - 64) * 40 + c];
        unsigned short hi, re;
        if (k < 64) {
            _Float16 h = (_Float16)v;
            float res = v - (float)h;
            _Float16 h2 = (_Float16)res;
            hi = *reinterpret_cast<unsigned short*>(&h);
            re = *reinterpret_cast<unsigned short*>(&h2);
        } else {
            hi = f2bf(v);
            re = f2bf(v - bf2f(hi));
        }
        int pos = c * 128 + (((k >> 3) ^ (c & 7)) << 3) + (k & 7);
        sBh[pos] = hi;
        sBr[pos] = re;
    }
    __syncthreads();

    int w = t >> 6;
    int lane = t & 63;
    int r = lane & 15;
    int q = lane >> 4;
    int m = w * 16 + r;
    // A frags: k-step s covers chunks s*4+q. s=0,1 -> f16 (agg2); s=2,3 -> bf16 (h1).
    f16x8  Af0 = *reinterpret_cast<const f16x8*>(&sA[m * 128 + (((0 + q) ^ (r & 7)) << 3)]);
    f16x8  Af1 = *reinterpret_cast<const f16x8*>(&sA[m * 128 + (((4 + q) ^ (r & 7)) << 3)]);
    bf16x8 Ab0 = *reinterpret_cast<const bf16x8*>(&sA[m * 128 + (((8 + q) ^ (r & 7)) << 3)]);
    bf16x8 Ab1 = *reinterpret_cast<const bf16x8*>(&sA[m * 128 + (((12 + q) ^ (r & 7)) << 3)]);

    f32x4 acc[3];
#pragma unroll
    for (int c = 0; c < 3; ++c) acc[c] = (f32x4)(0.0f);

#pragma unroll
    for (int c = 0; c < 3; ++c) {
        int cb = c * 16 + r;
        const unsigned short* bh = &sBh[cb * 128];
        const unsigned short* br = &sBr[cb * 128];
        f16x8  Bf0 = *reinterpret_cast<const f16x8*>(&bh[(((0 + q) ^ (r & 7)) << 3)]);
        f16x8  Bf1 = *reinterpret_cast<const f16x8*>(&bh[(((4 + q) ^ (r & 7)) << 3)]);
        bf16x8 Bb0 = *reinterpret_cast<const bf16x8*>(&bh[(((8 + q) ^ (r & 7)) << 3)]);
        bf16x8 Bb1 = *reinterpret_cast<const bf16x8*>(&bh[(((12 + q) ^ (r & 7)) << 3)]);
        f16x8  Rf0 = *reinterpret_cast<const f16x8*>(&br[(((0 + q) ^ (r & 7)) << 3)]);
        f16x8  Rf1 = *reinterpret_cast<const f16x8*>(&br[(((4 + q) ^ (r & 7)) << 3)]);
        bf16x8 Rb0 = *reinterpret_cast<const bf16x8*>(&br[(((8 + q) ^ (r & 7)) << 3)]);
        bf16x8 Rb1 = *reinterpret_cast<const bf16x8*>(&br[(((12 + q) ^ (r & 7)) << 3)]);
        acc[c] = __builtin_amdgcn_mfma_f32_16x16x32_f16(Af0, Bf0, acc[c], 0, 0, 0);
        acc[c] = __builtin_amdgcn_mfma_f32_16x16x32_f16(Af1, Bf1, acc[c], 0, 0, 0);
        acc[c] = __builtin_amdgcn_mfma_f32_16x16x32_f16(Af0, Rf0, acc[c], 0, 0, 0);
        acc[c] = __builtin_amdgcn_mfma_f32_16x16x32_f16(Af1, Rf1, acc[c], 0, 0, 0);
        acc[c] = __builtin_amdgcn_mfma_f32_16x16x32_bf16(Ab0, Bb0, acc[c], 0, 0, 0);
        acc[c] = __builtin_amdgcn_mfma_f32_16x16x32_bf16(Ab1, Bb1, acc[c], 0, 0, 0);
        acc[c] = __builtin_amdgcn_mfma_f32_16x16x32_bf16(Ab0, Rb0, acc[c], 0, 0, 0);
        acc[c] = __builtin_amdgcn_mfma_f32_16x16x32_bf16(Ab1, Rb1, acc[c], 0, 0, 0);
    }

    // Softmax epilogue. Row = w*16 + q*4 + j; cols = {r, 16+r, 32+r(<40 iff r<8)}.
    float bv0 = b2[r];
    float bv1 = b2[16 + r];
    float bv2 = (r < 8) ? b2[32 + r] : 0.0f;
#pragma unroll
    for (int j = 0; j < 4; ++j) {
        int node = blk * 64 + w * 16 + q * 4 + j;
        float v0 = acc[0][j] + bv0;
        float v1 = acc[1][j] + bv1;
        float v2 = (r < 8) ? (acc[2][j] + bv2) : -INFINITY;
        float mx = fmaxf(fmaxf(v0, v1), v2);
        mx = fmaxf(mx, __shfl_xor(mx, 1));
        mx = fmaxf(mx, __shfl_xor(mx, 2));
        mx = fmaxf(mx, __shfl_xor(mx, 4));
        mx = fmaxf(mx, __shfl_xor(mx, 8));
        float e0 = __expf(v0 - mx);
        float e1 = __expf(v1 - mx);
        float e2 = (r < 8) ? __expf(v2 - mx) : 0.0f;
        float s = e0 + e1 + e2;
        s += __shfl_xor(s, 1);
        s += __shfl_xor(s, 2);
        s += __shfl_xor(s, 4);
        s += __shfl_xor(s, 8);
        if (node < n) {
            float inv = 1.0f / s;
            out[(size_t)node * 40 + r] = e0 * inv;
            out[(size_t)node * 40 + 16 + r] = e1 * inv;
            if (r < 8) out[(size_t)node * 40 + 32 + r] = e2 * inv;
        }
    }
}

// ---------------- launch ----------------

extern "C" void kernel_launch(void* const* d_in, const int* in_sizes, int n_in,
                              void* d_out, int out_size, void* d_ws, size_t ws_size,
                              hipStream_t stream) {
    const float* x   = (const float*)d_in[0];
    const float* Wl1 = (const float*)d_in[1];
    const float* Wr1 = (const float*)d_in[2];
    const float* b1  = (const float*)d_in[3];
    const float* Wl2 = (const float*)d_in[4];
    const float* Wr2 = (const float*)d_in[5];
    const float* b2  = (const float*)d_in[6];
    const int* edge_src = (const int*)d_in[7];
    const int* edge_dst = (const int*)d_in[8];
    float* out = (float*)d_out;

    const int N = in_sizes[0] / 64;
    const int E = in_sizes[7];
    const int NBUCK = (N + (1 << BK_SHIFT) - 1) >> BK_SHIFT;   // 98
    size_t buf_bytes = (size_t)N * 64 * 4;
    int cap = E / NBUCK + E / (2 * NBUCK) + 1024;              // mean + 50% + slack
    int cap_max = (int)(buf_bytes / ((size_t)NBUCK * 4));
    if (cap > cap_max) cap = cap_max;

    size_t off = 0;
    auto carve = [&](size_t bytes) -> void* {
        void* p = (char*)d_ws + off;
        off = (off + bytes + 255) & ~(size_t)255;
        return p;
    };
    int*          row_ptr = (int*)carve((size_t)(N + 1) * 4);
    int*          bcursor = (int*)carve((size_t)NBUCK * 4);
    float*        dis     = (float*)carve((size_t)N * 4);
    float*        cnt_inv = (float*)carve((size_t)N * 4);
    int*          csr_src = (int*)carve((size_t)E * 4);
    char*         bufA    = (char*)carve(buf_bytes);
    char*         bufB    = (char*)carve(buf_bytes);
    float*        bufC    = (float*)carve(buf_bytes);          // temp
    unsigned int* temp    = (unsigned int*)bufC;
    (void)ws_size;

    // bf16/f16 sub-buffers (sequenced so nothing live overlaps):
    unsigned short* xb  = (unsigned short*)bufA;                         // x' = dis*x bf16
    unsigned short* p0b = (unsigned short*)(bufA + buf_bytes / 2);       // p0' bf16
    unsigned short* hb  = (unsigned short*)bufB;                         // h bf16
    unsigned short* hm  = (unsigned short*)bufA;                         // mean(h) f16 (xb dead)
    unsigned short* h1b = (unsigned short*)(bufA + buf_bytes / 2);       // h1 bf16 (p0b dead)
    unsigned short* hm2 = (unsigned short*)(bufB + buf_bytes / 2);       // mean(h1) f16

    const int nb_node = (N + 3) / 4;
    const int nb_gemm = (N + 63) / 64;
    const int n4 = N * 64 / 4;

    // CSR build (bcursor zeroed via async memset; partition uses relative cursors)
    hipMemsetAsync(bcursor, 0, (size_t)NBUCK * 4, stream);
    partition_kernel<<<256, 256, 0, stream>>>(edge_src, edge_dst, bcursor, temp, E, NBUCK, cap);
    bucket_csr_kernel<<<NBUCK, 256, 0, stream>>>(temp, bcursor, row_ptr, dis, cnt_inv,
                                                 csr_src, N, cap, NBUCK, E);

    // x' = bf16(dis * x)
    f2bf_scale_kernel<<<(n4 + 255) / 256, 256, 0, stream>>>((const float4*)x, (ushort4*)xb,
                                                            dis, n4);
    // KProp x2 (pre-scaled): p0' = dis^2 * sum x'[s] ; h = dis * sum p0'[s]
    prop4bf_kernel<2><<<nb_node, 256, 0, stream>>>((const ushort4*)xb, (ushort4*)p0b,
                                                   row_ptr, csr_src, dis, N);
    prop4bf_kernel<1><<<nb_node, 256, 0, stream>>>((const ushort4*)p0b, (ushort4*)hb,
                                                   row_ptr, csr_src, dis, N);
    // hm = mean(h) -> f16
    prop_mean_plain_kernel<<<nb_node, 256, 0, stream>>>((const ushort4*)hb, (ushort4*)hm,
                                                        row_ptr, csr_src, cnt_inv, N);
    // h1 = selu([hm|h] @ [Wl1;Wr1] + b1) -> bf16
    gemm1_selu_kernel<<<nb_gemm, 256, 0, stream>>>(hm, hb, Wl1, Wr1, b1, h1b, N);
    // hm2 = mean(h1) -> f16
    prop_mean_plain_kernel<<<nb_node, 256, 0, stream>>>((const ushort4*)h1b, (ushort4*)hm2,
                                                        row_ptr, csr_src, cnt_inv, N);
    // out = softmax([hm2|h1] @ [Wl2;Wr2] + b2)
    gemm2_softmax_kernel<<<nb_gemm, 256, 0, stream>>>(hm2, h1b, Wl2, Wr2, b2, out, N);
}

// Round 7
// 359.036 us; speedup vs baseline: 1.2121x; 1.0217x over previous
//
#include <hip/hip_runtime.h>
#include <hip/hip_bf16.h>
#include <math.h>

// Node classifier: KProp(K=2, gcn_norm) -> SAGEConv(64->64)+selu -> SAGEConv(64->40) -> softmax
// N=100000, E=1600000, D=H=64, C=40.
//
// R19 = R18 with CSR-build parallelism fixed (bucket_csr was 41.7us @ 3.6% occupancy):
//   bucket_csr_kernel: 256 -> 1024 threads/block (thread t owns node t of the bucket;
//   count/scatter passes 64 -> 16 iters; 16 waves/block hide LDS-atomic latency)
//   partition_kernel: grid 256 -> 1024 blocks (4 blocks/CU latency hiding)

#define RFL(x) __builtin_amdgcn_readfirstlane(x)
#define BK_SHIFT 10        // coarse bucket = dst>>10 (1024 nodes)
#define MAXBUCK 256

typedef short bf16x8 __attribute__((ext_vector_type(8)));
typedef _Float16 f16x8 __attribute__((ext_vector_type(8)));
typedef float f32x4 __attribute__((ext_vector_type(4)));
typedef unsigned short ushort8v __attribute__((ext_vector_type(8)));

__device__ __forceinline__ float bf2f(unsigned short u) {
    return __uint_as_float((unsigned)u << 16);
}
__device__ __forceinline__ unsigned short f2bf(float f) {
    __hip_bfloat16 b = __float2bfloat16(f);   // RTN
    return *reinterpret_cast<unsigned short*>(&b);
}
__device__ __forceinline__ unsigned short f2h(float f) {
    _Float16 h = (_Float16)f;                 // RTN
    return *reinterpret_cast<unsigned short*>(&h);
}

// ---------------- CSR build ----------------

// Phase 1: block-private coarse bucket partition; packed u32 (src<<10 | dst&1023).
// bcursor[] starts at 0 (memset); holds per-bucket relative fill count.
__global__ __launch_bounds__(256) void partition_kernel(const int* __restrict__ src,
                                                        const int* __restrict__ dst,
                                                        int* __restrict__ bcursor,
                                                        unsigned int* __restrict__ temp,
                                                        int e, int nbuck, int cap) {
    __shared__ int bc[MAXBUCK];
    int t = threadIdx.x;
    int chunk = (e + gridDim.x - 1) / gridDim.x;
    int base = blockIdx.x * chunk;
    int cnt = e - base;
    if (cnt > chunk) cnt = chunk;
    if (cnt < 0) cnt = 0;
    for (int j = t; j < nbuck; j += 256) bc[j] = 0;
    __syncthreads();
    for (int i = t; i < cnt; i += 256) {
        int d = dst[base + i];
        atomicAdd(&bc[d >> BK_SHIFT], 1);
    }
    __syncthreads();
    for (int j = t; j < nbuck; j += 256) {
        int c = bc[j];
        bc[j] = (c > 0) ? (atomicAdd(&bcursor[j], c) + j * cap) : 0;
    }
    __syncthreads();
    for (int i = t; i < cnt; i += 256) {
        int s = src[base + i];
        int d = dst[base + i];
        int bk = d >> BK_SHIFT;
        int p = atomicAdd(&bc[bk], 1);
        if (p < (bk + 1) * cap) temp[p] = ((unsigned int)s << BK_SHIFT) | (unsigned int)(d & 1023);
    }
}

// Phase 2: per-bucket counting sort by node_local + deg/dis/cnt_inv/row_ptr.
// 1024 threads: thread t owns node (b<<10)+t. Hillis-Steele scans over 1024.
__global__ __launch_bounds__(1024) void bucket_csr_kernel(const unsigned int* __restrict__ temp,
                                                          const int* __restrict__ bcursor,
                                                          int* __restrict__ row_ptr,
                                                          float* __restrict__ dis,
                                                          float* __restrict__ cnt_inv,
                                                          int* __restrict__ csr_src,
                                                          int n, int cap, int nbuck, int e) {
    __shared__ int cnt3[1024];
    __shared__ int part[1024];
    int b = blockIdx.x;
    int t = threadIdx.x;
    int nbeg = b << BK_SHIFT;

    // Scan bucket sizes -> bbase (inclusive scan over nbuck entries, zero-padded).
    int cj = 0;
    if (t < nbuck) {
        cj = bcursor[t];
        if (cj > cap) cj = cap;
    }
    part[t] = cj;
    __syncthreads();
    for (int off = 1; off < 1024; off <<= 1) {
        int u = (t >= off) ? part[t - off] : 0;
        __syncthreads();
        part[t] += u;
        __syncthreads();
    }
    int cntb = bcursor[b];
    if (cntb > cap) cntb = cap;
    int bbase = part[b] - cntb;
    __syncthreads();

    // Count node-local occurrences.
    cnt3[t] = 0;
    __syncthreads();
    const unsigned int* tb = temp + (size_t)b * cap;
    for (int i = t; i < cntb; i += 1024) {
        atomicAdd(&cnt3[tb[i] & 1023u], 1);
    }
    __syncthreads();

    int d = cnt3[t];
    int node = nbeg + t;
    if (node < n) {
        float fd = (float)d;
        dis[node] = (d > 0) ? rsqrtf(fd) : 0.0f;
        cnt_inv[node] = 1.0f / fmaxf(fd, 1.0f);
    }

    // Exclusive prefix of per-node counts.
    part[t] = d;
    __syncthreads();
    for (int off = 1; off < 1024; off <<= 1) {
        int u = (t >= off) ? part[t - off] : 0;
        __syncthreads();
        part[t] += u;
        __syncthreads();
    }
    int ex = part[t] - d;
    cnt3[t] = ex;
    if (node < n) row_ptr[node] = bbase + ex;
    if (b == nbuck - 1 && t == 0) row_ptr[n] = e;
    __syncthreads();

    // Scatter.
    for (int i = t; i < cntb; i += 1024) {
        unsigned int ed = tb[i];
        int pos = atomicAdd(&cnt3[ed & 1023u], 1);
        csr_src[bbase + pos] = (int)(ed >> BK_SHIFT);
    }
}

// ---------------- fp32 -> bf16 convert, pre-scaled by dis[node] ----------------
__global__ void f2bf_scale_kernel(const float4* __restrict__ in, ushort4* __restrict__ out,
                                  const float* __restrict__ dis, int n4) {
    int i = blockIdx.x * blockDim.x + threadIdx.x;
    if (i < n4) {
        float d = dis[i >> 4];
        float4 v = in[i];
        ushort4 u;
        u.x = f2bf(v.x * d); u.y = f2bf(v.y * d); u.z = f2bf(v.z * d); u.w = f2bf(v.w * d);
        out[i] = u;
    }
}

// ---------------- KProp propagation: unweighted row-sum, final scale dis^POW ----------------
// Wave per node. lane = g*16 + l: edge slot g (0..3), feature quad l (0..15).
// POW==2: out = dis^2 * sum (round 1, input pre-scaled x'); POW==1: out = dis * sum (round 2).
template <int POW>
__global__ __launch_bounds__(256) void prop4bf_kernel(const ushort4* __restrict__ in4u,
                                                      ushort4* __restrict__ out4u,
                                                      const int* __restrict__ row_ptr,
                                                      const int* __restrict__ csr_src,
                                                      const float* __restrict__ dis,
                                                      int n) {
    int lane = threadIdx.x & 63;
    int g = lane >> 4;
    int l = lane & 15;
    int node = RFL(blockIdx.x * 4 + (threadIdx.x >> 6));
    if (node >= n) return;
    int beg = row_ptr[node];
    int end = row_ptr[node + 1];
    float4 acc = make_float4(0.f, 0.f, 0.f, 0.f);
    int j = beg;
    for (; j + 16 <= end; j += 16) {
        int s[4];
        ushort4 u[4];
#pragma unroll
        for (int q = 0; q < 4; ++q) s[q] = csr_src[j + q * 4 + g];
#pragma unroll
        for (int q = 0; q < 4; ++q) u[q] = in4u[(size_t)s[q] * 16 + l];
#pragma unroll
        for (int q = 0; q < 4; ++q) {
            acc.x += bf2f(u[q].x);
            acc.y += bf2f(u[q].y);
            acc.z += bf2f(u[q].z);
            acc.w += bf2f(u[q].w);
        }
    }
    for (; j + 8 <= end; j += 8) {
        int s[2];
        ushort4 u[2];
#pragma unroll
        for (int q = 0; q < 2; ++q) s[q] = csr_src[j + q * 4 + g];
#pragma unroll
        for (int q = 0; q < 2; ++q) u[q] = in4u[(size_t)s[q] * 16 + l];
#pragma unroll
        for (int q = 0; q < 2; ++q) {
            acc.x += bf2f(u[q].x);
            acc.y += bf2f(u[q].y);
            acc.z += bf2f(u[q].z);
            acc.w += bf2f(u[q].w);
        }
    }
    for (; j < end; j += 4) {
        int idx = j + g;
        bool valid = idx < end;
        int s = csr_src[valid ? idx : (end - 1)];
        float w = valid ? 1.0f : 0.0f;
        ushort4 u = in4u[(size_t)s * 16 + l];
        acc.x += w * bf2f(u.x);
        acc.y += w * bf2f(u.y);
        acc.z += w * bf2f(u.z);
        acc.w += w * bf2f(u.w);
    }
    acc.x += __shfl_xor(acc.x, 16); acc.x += __shfl_xor(acc.x, 32);
    acc.y += __shfl_xor(acc.y, 16); acc.y += __shfl_xor(acc.y, 32);
    acc.z += __shfl_xor(acc.z, 16); acc.z += __shfl_xor(acc.z, 32);
    acc.w += __shfl_xor(acc.w, 16); acc.w += __shfl_xor(acc.w, 32);
    if (g == 0) {
        float d = dis[node];
        float sc = (POW == 2) ? d * d : d;
        ushort4 o;
        o.x = f2bf(acc.x * sc);
        o.y = f2bf(acc.y * sc);
        o.z = f2bf(acc.z * sc);
        o.w = f2bf(acc.w * sc);
        out4u[(size_t)node * 16 + l] = o;
    }
}

// ---------------- plain mean-agg over bf16 rows, f16 out ----------------
__global__ __launch_bounds__(256) void prop_mean_plain_kernel(const ushort4* __restrict__ in4u,
                                                              ushort4* __restrict__ out4u,
                                                              const int* __restrict__ row_ptr,
                                                              const int* __restrict__ csr_src,
                                                              const float* __restrict__ cnt_inv,
                                                              int n) {
    int lane = threadIdx.x & 63;
    int g = lane >> 4;
    int l = lane & 15;
    int node = RFL(blockIdx.x * 4 + (threadIdx.x >> 6));
    if (node >= n) return;
    int beg = row_ptr[node];
    int end = row_ptr[node + 1];
    float4 acc = make_float4(0.f, 0.f, 0.f, 0.f);
    int j = beg;
    for (; j + 16 <= end; j += 16) {
        int s[4];
        ushort4 u[4];
#pragma unroll
        for (int q = 0; q < 4; ++q) s[q] = csr_src[j + q * 4 + g];
#pragma unroll
        for (int q = 0; q < 4; ++q) u[q] = in4u[(size_t)s[q] * 16 + l];
#pragma unroll
        for (int q = 0; q < 4; ++q) {
            acc.x += bf2f(u[q].x);
            acc.y += bf2f(u[q].y);
            acc.z += bf2f(u[q].z);
            acc.w += bf2f(u[q].w);
        }
    }
    for (; j + 8 <= end; j += 8) {
        int s[2];
        ushort4 u[2];
#pragma unroll
        for (int q = 0; q < 2; ++q) s[q] = csr_src[j + q * 4 + g];
#pragma unroll
        for (int q = 0; q < 2; ++q) u[q] = in4u[(size_t)s[q] * 16 + l];
#pragma unroll
        for (int q = 0; q < 2; ++q) {
            acc.x += bf2f(u[q].x);
            acc.y += bf2f(u[q].y);
            acc.z += bf2f(u[q].z);
            acc.w += bf2f(u[q].w);
        }
    }
    for (; j < end; j += 4) {
        int idx = j + g;
        bool valid = idx < end;
        int s = csr_src[valid ? idx : (end - 1)];
        float w = valid ? 1.0f : 0.0f;
        ushort4 u = in4u[(size_t)s * 16 + l];
        acc.x += w * bf2f(u.x);
        acc.y += w * bf2f(u.y);
        acc.z += w * bf2f(u.z);
        acc.w += w * bf2f(u.w);
    }
    acc.x += __shfl_xor(acc.x, 16); acc.x += __shfl_xor(acc.x, 32);
    acc.y += __shfl_xor(acc.y, 16); acc.y += __shfl_xor(acc.y, 32);
    acc.z += __shfl_xor(acc.z, 16); acc.z += __shfl_xor(acc.z, 32);
    acc.w += __shfl_xor(acc.w, 16); acc.w += __shfl_xor(acc.w, 32);
    if (g == 0) {
        float sc = cnt_inv[node];
        ushort4 o;
        o.x = f2h(acc.x * sc);
        o.y = f2h(acc.y * sc);
        o.z = f2h(acc.z * sc);
        o.w = f2h(acc.w * sc);
        out4u[(size_t)node * 16 + l] = o;
    }
}

// ---------------- fused layer-1 GEMM + selu ----------------
// h1 = selu([hm(f16)|h(bf16)] @ [Wl1;Wr1] + b1), k=128, 64 cols, bf16 out.
// Block = 64 nodes, 4 waves; wave = 16-node band x 64 cols (4 frags).
__global__ __launch_bounds__(256) void gemm1_selu_kernel(const unsigned short* __restrict__ aggf,
                                                         const unsigned short* __restrict__ h,
                                                         const float* __restrict__ Wl1,
                                                         const float* __restrict__ Wr1,
                                                         const float* __restrict__ b1,
                                                         unsigned short* __restrict__ h1,
                                                         int n) {
    __shared__ unsigned short sA[64 * 128];       // [m][k] swizzled: k<64 f16 hm, k>=64 bf16 h
    __shared__ unsigned short sBh[64 * 128];      // [c][k] swizzled, hi
    __shared__ unsigned short sBr[64 * 128];      // [c][k] swizzled, residual
    int t = threadIdx.x;
    int blk = blockIdx.x;

    // Stage A: 64 rows x 16 chunks of 16B.
#pragma unroll
    for (int i = 0; i < 4; ++i) {
        int idx = i * 256 + t;
        int m = idx >> 4;
        int kb = idx & 15;
        int node = blk * 64 + m;
        if (node >= n) node = n - 1;
        const unsigned short* srcp = (kb < 8) ? aggf : h;
        ushort8v v = *reinterpret_cast<const ushort8v*>(srcp + (size_t)node * 64 + (kb & 7) * 8);
        *reinterpret_cast<ushort8v*>(&sA[m * 128 + ((kb ^ (m & 7)) << 3)]) = v;
    }
    // Stage B: 64 cols x 128 k. k<64: f16 split of Wl1; k>=64: bf16 split of Wr1.
    for (int idx = t; idx < 64 * 128; idx += 256) {
        int k = idx >> 6;
        int c = idx & 63;
        float v = (k < 64) ? Wl1[k * 64 + c] : Wr1[(k - 64) * 64 + c];
        unsigned short hi, re;
        if (k < 64) {
            _Float16 hh = (_Float16)v;
            float res = v - (float)hh;
            _Float16 h2 = (_Float16)res;
            hi = *reinterpret_cast<unsigned short*>(&hh);
            re = *reinterpret_cast<unsigned short*>(&h2);
        } else {
            hi = f2bf(v);
            re = f2bf(v - bf2f(hi));
        }
        int pos = c * 128 + (((k >> 3) ^ (c & 7)) << 3) + (k & 7);
        sBh[pos] = hi;
        sBr[pos] = re;
    }
    __syncthreads();

    int w = t >> 6;
    int lane = t & 63;
    int r = lane & 15;
    int q = lane >> 4;
    int m = w * 16 + r;
    // A frags: k-step s covers chunks s*4+q. s=0,1 -> f16 (hm); s=2,3 -> bf16 (h).
    f16x8  Af0 = *reinterpret_cast<const f16x8*>(&sA[m * 128 + (((0 + q) ^ (r & 7)) << 3)]);
    f16x8  Af1 = *reinterpret_cast<const f16x8*>(&sA[m * 128 + (((4 + q) ^ (r & 7)) << 3)]);
    bf16x8 Ab0 = *reinterpret_cast<const bf16x8*>(&sA[m * 128 + (((8 + q) ^ (r & 7)) << 3)]);
    bf16x8 Ab1 = *reinterpret_cast<const bf16x8*>(&sA[m * 128 + (((12 + q) ^ (r & 7)) << 3)]);

    f32x4 acc[4];
#pragma unroll
    for (int c = 0; c < 4; ++c) acc[c] = (f32x4)(0.0f);

#pragma unroll
    for (int c = 0; c < 4; ++c) {
        int cb = c * 16 + r;
        const unsigned short* bh = &sBh[cb * 128];
        const unsigned short* br = &sBr[cb * 128];
        f16x8  Bf0 = *reinterpret_cast<const f16x8*>(&bh[(((0 + q) ^ (r & 7)) << 3)]);
        f16x8  Bf1 = *reinterpret_cast<const f16x8*>(&bh[(((4 + q) ^ (r & 7)) << 3)]);
        bf16x8 Bb0 = *reinterpret_cast<const bf16x8*>(&bh[(((8 + q) ^ (r & 7)) << 3)]);
        bf16x8 Bb1 = *reinterpret_cast<const bf16x8*>(&bh[(((12 + q) ^ (r & 7)) << 3)]);
        f16x8  Rf0 = *reinterpret_cast<const f16x8*>(&br[(((0 + q) ^ (r & 7)) << 3)]);
        f16x8  Rf1 = *reinterpret_cast<const f16x8*>(&br[(((4 + q) ^ (r & 7)) << 3)]);
        bf16x8 Rb0 = *reinterpret_cast<const bf16x8*>(&br[(((8 + q) ^ (r & 7)) << 3)]);
        bf16x8 Rb1 = *reinterpret_cast<const bf16x8*>(&br[(((12 + q) ^ (r & 7)) << 3)]);
        acc[c] = __builtin_amdgcn_mfma_f32_16x16x32_f16(Af0, Bf0, acc[c], 0, 0, 0);
        acc[c] = __builtin_amdgcn_mfma_f32_16x16x32_f16(Af1, Bf1, acc[c], 0, 0, 0);
        acc[c] = __builtin_amdgcn_mfma_f32_16x16x32_f16(Af0, Rf0, acc[c], 0, 0, 0);
        acc[c] = __builtin_amdgcn_mfma_f32_16x16x32_f16(Af1, Rf1, acc[c], 0, 0, 0);
        acc[c] = __builtin_amdgcn_mfma_f32_16x16x32_bf16(Ab0, Bb0, acc[c], 0, 0, 0);
        acc[c] = __builtin_amdgcn_mfma_f32_16x16x32_bf16(Ab1, Bb1, acc[c], 0, 0, 0);
        acc[c] = __builtin_amdgcn_mfma_f32_16x16x32_bf16(Ab0, Rb0, acc[c], 0, 0, 0);
        acc[c] = __builtin_amdgcn_mfma_f32_16x16x32_bf16(Ab1, Rb1, acc[c], 0, 0, 0);
    }

    // Selu epilogue. Row = w*16 + q*4 + j; col = c*16 + r.
    const float scale = 1.0507009873554805f;
    const float alpha = 1.6732632423543772f;
#pragma unroll
    for (int c = 0; c < 4; ++c) {
        int col = c * 16 + r;
        float bv = b1[col];
#pragma unroll
        for (int j = 0; j < 4; ++j) {
            int node = blk * 64 + w * 16 + q * 4 + j;
            if (node < n) {
                float v = acc[c][j] + bv;
                v = scale * (v > 0.0f ? v : alpha * expm1f(v));
                h1[(size_t)node * 64 + col] = f2bf(v);
            }
        }
    }
}

// ---------------- fused layer-2 GEMM + softmax ----------------
// out = softmax([agg2(f16)|h1(bf16)] @ [Wl2;Wr2] + b2), k=128, 40 cols (padded to 48).
// Block = 64 nodes, 4 waves; wave = 16-node band x 48 cols (3 frags).
__global__ __launch_bounds__(256) void gemm2_softmax_kernel(const unsigned short* __restrict__ aggf,
                                                            const unsigned short* __restrict__ h1,
                                                            const float* __restrict__ Wl2,
                                                            const float* __restrict__ Wr2,
                                                            const float* __restrict__ b2,
                                                            float* __restrict__ out,
                                                            int n) {
    __shared__ unsigned short sA[64 * 128];       // [m][k] swizzled: k<64 f16 agg2, k>=64 bf16 h1
    __shared__ unsigned short sBh[48 * 128];      // [c][k] swizzled, hi
    __shared__ unsigned short sBr[48 * 128];      // [c][k] swizzled, residual
    int t = threadIdx.x;
    int blk = blockIdx.x;

    // Stage A: 64 rows x 16 chunks of 16B.
#pragma unroll
    for (int i = 0; i < 4; ++i) {
        int idx = i * 256 + t;
        int m = idx >> 4;
        int kb = idx & 15;
        int node = blk * 64 + m;
        if (node >= n) node = n - 1;
        const unsigned short* srcp = (kb < 8) ? aggf : h1;
        ushort8v v = *reinterpret_cast<const ushort8v*>(srcp + (size_t)node * 64 + (kb & 7) * 8);
        *reinterpret_cast<ushort8v*>(&sA[m * 128 + ((kb ^ (m & 7)) << 3)]) = v;
    }
    // Stage B: 48 cols x 128 k. k<64: f16 split of Wl2; k>=64: bf16 split of Wr2. cols>=40 zero.
    for (int idx = t; idx < 48 * 128; idx += 256) {
        int k = idx / 48;
        int c = idx - k * 48;
        float v = 0.0f;
        if (c < 40) v = (k < 64) ? Wl2[k * 40 + c] : Wr2[(k - 64) * 40 + c];
        unsigned short hi, re;
        if (k < 64) {
            _Float16 h = (_Float16)v;
            float res = v - (float)h;
            _Float16 h2 = (_Float16)res;
            hi = *reinterpret_cast<unsigned short*>(&h);
            re = *reinterpret_cast<unsigned short*>(&h2);
        } else {
            hi = f2bf(v);
            re = f2bf(v - bf2f(hi));
        }
        int pos = c * 128 + (((k >> 3) ^ (c & 7)) << 3) + (k & 7);
        sBh[pos] = hi;
        sBr[pos] = re;
    }
    __syncthreads();

    int w = t >> 6;
    int lane = t & 63;
    int r = lane & 15;
    int q = lane >> 4;
    int m = w * 16 + r;
    // A frags: k-step s covers chunks s*4+q. s=0,1 -> f16 (agg2); s=2,3 -> bf16 (h1).
    f16x8  Af0 = *reinterpret_cast<const f16x8*>(&sA[m * 128 + (((0 + q) ^ (r & 7)) << 3)]);
    f16x8  Af1 = *reinterpret_cast<const f16x8*>(&sA[m * 128 + (((4 + q) ^ (r & 7)) << 3)]);
    bf16x8 Ab0 = *reinterpret_cast<const bf16x8*>(&sA[m * 128 + (((8 + q) ^ (r & 7)) << 3)]);
    bf16x8 Ab1 = *reinterpret_cast<const bf16x8*>(&sA[m * 128 + (((12 + q) ^ (r & 7)) << 3)]);

    f32x4 acc[3];
#pragma unroll
    for (int c = 0; c < 3; ++c) acc[c] = (f32x4)(0.0f);

#pragma unroll
    for (int c = 0; c < 3; ++c) {
        int cb = c * 16 + r;
        const unsigned short* bh = &sBh[cb * 128];
        const unsigned short* br = &sBr[cb * 128];
        f16x8  Bf0 = *reinterpret_cast<const f16x8*>(&bh[(((0 + q) ^ (r & 7)) << 3)]);
        f16x8  Bf1 = *reinterpret_cast<const f16x8*>(&bh[(((4 + q) ^ (r & 7)) << 3)]);
        bf16x8 Bb0 = *reinterpret_cast<const bf16x8*>(&bh[(((8 + q) ^ (r & 7)) << 3)]);
        bf16x8 Bb1 = *reinterpret_cast<const bf16x8*>(&bh[(((12 + q) ^ (r & 7)) << 3)]);
        f16x8  Rf0 = *reinterpret_cast<const f16x8*>(&br[(((0 + q) ^ (r & 7)) << 3)]);
        f16x8  Rf1 = *reinterpret_cast<const f16x8*>(&br[(((4 + q) ^ (r & 7)) << 3)]);
        bf16x8 Rb0 = *reinterpret_cast<const bf16x8*>(&br[(((8 + q) ^ (r & 7)) << 3)]);
        bf16x8 Rb1 = *reinterpret_cast<const bf16x8*>(&br[(((12 + q) ^ (r & 7)) << 3)]);
        acc[c] = __builtin_amdgcn_mfma_f32_16x16x32_f16(Af0, Bf0, acc[c], 0, 0, 0);
        acc[c] = __builtin_amdgcn_mfma_f32_16x16x32_f16(Af1, Bf1, acc[c], 0, 0, 0);
        acc[c] = __builtin_amdgcn_mfma_f32_16x16x32_f16(Af0, Rf0, acc[c], 0, 0, 0);
        acc[c] = __builtin_amdgcn_mfma_f32_16x16x32_f16(Af1, Rf1, acc[c], 0, 0, 0);
        acc[c] = __builtin_amdgcn_mfma_f32_16x16x32_bf16(Ab0, Bb0, acc[c], 0, 0, 0);
        acc[c] = __builtin_amdgcn_mfma_f32_16x16x32_bf16(Ab1, Bb1, acc[c], 0, 0, 0);
        acc[c] = __builtin_amdgcn_mfma_f32_16x16x32_bf16(Ab0, Rb0, acc[c], 0, 0, 0);
        acc[c] = __builtin_amdgcn_mfma_f32_16x16x32_bf16(Ab1, Rb1, acc[c], 0, 0, 0);
    }

    // Softmax epilogue. Row = w*16 + q*4 + j; cols = {r, 16+r, 32+r(<40 iff r<8)}.
    float bv0 = b2[r];
    float bv1 = b2[16 + r];
    float bv2 = (r < 8) ? b2[32 + r] : 0.0f;
#pragma unroll
    for (int j = 0; j < 4; ++j) {
        int node = blk * 64 + w * 16 + q * 4 + j;
        float v0 = acc[0][j] + bv0;
        float v1 = acc[1][j] + bv1;
        float v2 = (r < 8) ? (acc[2][j] + bv2) : -INFINITY;
        float mx = fmaxf(fmaxf(v0, v1), v2);
        mx = fmaxf(mx, __shfl_xor(mx, 1));
        mx = fmaxf(mx, __shfl_xor(mx, 2));
        mx = fmaxf(mx, __shfl_xor(mx, 4));
        mx = fmaxf(mx, __shfl_xor(mx, 8));
        float e0 = __expf(v0 - mx);
        float e1 = __expf(v1 - mx);
        float e2 = (r < 8) ? __expf(v2 - mx) : 0.0f;
        float s = e0 + e1 + e2;
        s += __shfl_xor(s, 1);
        s += __shfl_xor(s, 2);
        s += __shfl_xor(s, 4);
        s += __shfl_xor(s, 8);
        if (node < n) {
            float inv = 1.0f / s;
            out[(size_t)node * 40 + r] = e0 * inv;
            out[(size_t)node * 40 + 16 + r] = e1 * inv;
            if (r < 8) out[(size_t)node * 40 + 32 + r] = e2 * inv;
        }
    }
}

// ---------------- launch ----------------

extern "C" void kernel_launch(void* const* d_in, const int* in_sizes, int n_in,
                              void* d_out, int out_size, void* d_ws, size_t ws_size,
                              hipStream_t stream) {
    const float* x   = (const float*)d_in[0];
    const float* Wl1 = (const float*)d_in[1];
    const float* Wr1 = (const float*)d_in[2];
    const float* b1  = (const float*)d_in[3];
    const float* Wl2 = (const float*)d_in[4];
    const float* Wr2 = (const float*)d_in[5];
    const float* b2  = (const float*)d_in[6];
    const int* edge_src = (const int*)d_in[7];
    const int* edge_dst = (const int*)d_in[8];
    float* out = (float*)d_out;

    const int N = in_sizes[0] / 64;
    const int E = in_sizes[7];
    const int NBUCK = (N + (1 << BK_SHIFT) - 1) >> BK_SHIFT;   // 98
    size_t buf_bytes = (size_t)N * 64 * 4;
    int cap = E / NBUCK + E / (2 * NBUCK) + 1024;              // mean + 50% + slack
    int cap_max = (int)(buf_bytes / ((size_t)NBUCK * 4));
    if (cap > cap_max) cap = cap_max;

    size_t off = 0;
    auto carve = [&](size_t bytes) -> void* {
        void* p = (char*)d_ws + off;
        off = (off + bytes + 255) & ~(size_t)255;
        return p;
    };
    int*          row_ptr = (int*)carve((size_t)(N + 1) * 4);
    int*          bcursor = (int*)carve((size_t)NBUCK * 4);
    float*        dis     = (float*)carve((size_t)N * 4);
    float*        cnt_inv = (float*)carve((size_t)N * 4);
    int*          csr_src = (int*)carve((size_t)E * 4);
    char*         bufA    = (char*)carve(buf_bytes);
    char*         bufB    = (char*)carve(buf_bytes);
    float*        bufC    = (float*)carve(buf_bytes);          // temp
    unsigned int* temp    = (unsigned int*)bufC;
    (void)ws_size;

    // bf16/f16 sub-buffers (sequenced so nothing live overlaps):
    unsigned short* xb  = (unsigned short*)bufA;                         // x' = dis*x bf16
    unsigned short* p0b = (unsigned short*)(bufA + buf_bytes / 2);       // p0' bf16
    unsigned short* hb  = (unsigned short*)bufB;                         // h bf16
    unsigned short* hm  = (unsigned short*)bufA;                         // mean(h) f16 (xb dead)
    unsigned short* h1b = (unsigned short*)(bufA + buf_bytes / 2);       // h1 bf16 (p0b dead)
    unsigned short* hm2 = (unsigned short*)(bufB + buf_bytes / 2);       // mean(h1) f16

    const int nb_node = (N + 3) / 4;
    const int nb_gemm = (N + 63) / 64;
    const int n4 = N * 64 / 4;

    // CSR build (bcursor zeroed via async memset; partition uses relative cursors)
    hipMemsetAsync(bcursor, 0, (size_t)NBUCK * 4, stream);
    partition_kernel<<<1024, 256, 0, stream>>>(edge_src, edge_dst, bcursor, temp, E, NBUCK, cap);
    bucket_csr_kernel<<<NBUCK, 1024, 0, stream>>>(temp, bcursor, row_ptr, dis, cnt_inv,
                                                  csr_src, N, cap, NBUCK, E);

    // x' = bf16(dis * x)
    f2bf_scale_kernel<<<(n4 + 255) / 256, 256, 0, stream>>>((const float4*)x, (ushort4*)xb,
                                                            dis, n4);
    // KProp x2 (pre-scaled): p0' = dis^2 * sum x'[s] ; h = dis * sum p0'[s]
    prop4bf_kernel<2><<<nb_node, 256, 0, stream>>>((const ushort4*)xb, (ushort4*)p0b,
                                                   row_ptr, csr_src, dis, N);
    prop4bf_kernel<1><<<nb_node, 256, 0, stream>>>((const ushort4*)p0b, (ushort4*)hb,
                                                   row_ptr, csr_src, dis, N);
    // hm = mean(h) -> f16
    prop_mean_plain_kernel<<<nb_node, 256, 0, stream>>>((const ushort4*)hb, (ushort4*)hm,
                                                        row_ptr, csr_src, cnt_inv, N);
    // h1 = selu([hm|h] @ [Wl1;Wr1] + b1) -> bf16
    gemm1_selu_kernel<<<nb_gemm, 256, 0, stream>>>(hm, hb, Wl1, Wr1, b1, h1b, N);
    // hm2 = mean(h1) -> f16
    prop_mean_plain_kernel<<<nb_node, 256, 0, stream>>>((const ushort4*)h1b, (ushort4*)hm2,
                                                        row_ptr, csr_src, cnt_inv, N);
    // out = softmax([hm2|h1] @ [Wl2;Wr2] + b2)
    gemm2_softmax_kernel<<<nb_gemm, 256, 0, stream>>>(hm2, h1b, Wl2, Wr2, b2, out, N);
}